// Round 1
// baseline (7770.938 us; speedup 1.0000x reference)
//
#include <hip/hip_runtime.h>

#define Bn   4
#define Nn   3072
#define DIMn 768
#define Hn   3
#define HDn  256
#define BHn  12
#define Dn   262
#define SCALE 0.0625f   // HD^-0.5 = 1/16

// ---------------------------------------------------------------------------
// K1: qkv = x @ W_qkv^T   (rows = B*N = 12288, cols = 2304, K = 768)
// Writes q[bh][n][hd], k[bh][n][hd], vcat[bh][n][hd] (cols 0..255 of vcat).
// ---------------------------------------------------------------------------
__global__ __launch_bounds__(256) void qkv_gemm(const float* __restrict__ x,
                                                const float* __restrict__ W,
                                                float* __restrict__ q,
                                                float* __restrict__ k,
                                                float* __restrict__ vcat) {
    __shared__ float As[16][68];
    __shared__ float Bs[16][68];
    int tid = threadIdx.x;
    int rb = blockIdx.y * 64;       // row base in [0, 12288)
    int cb = blockIdx.x * 64;       // col base in [0, 2304)
    int lr = tid >> 2;              // 0..63
    int lk = (tid & 3) << 2;        // 0,4,8,12
    int ty = tid >> 4, tx = tid & 15;
    float acc[4][4] = {};

    for (int k0 = 0; k0 < DIMn; k0 += 16) {
        float4 av = *(const float4*)(x + (size_t)(rb + lr) * DIMn + k0 + lk);
        float4 bv = *(const float4*)(W + (size_t)(cb + lr) * DIMn + k0 + lk);
        As[lk+0][lr]=av.x; As[lk+1][lr]=av.y; As[lk+2][lr]=av.z; As[lk+3][lr]=av.w;
        Bs[lk+0][lr]=bv.x; Bs[lk+1][lr]=bv.y; Bs[lk+2][lr]=bv.z; Bs[lk+3][lr]=bv.w;
        __syncthreads();
        #pragma unroll
        for (int kk = 0; kk < 16; ++kk) {
            float a[4], b[4];
            #pragma unroll
            for (int i = 0; i < 4; ++i) a[i] = As[kk][ty*4+i];
            #pragma unroll
            for (int j = 0; j < 4; ++j) b[j] = Bs[kk][tx*4+j];
            #pragma unroll
            for (int i = 0; i < 4; ++i)
                #pragma unroll
                for (int j = 0; j < 4; ++j) acc[i][j] += a[i]*b[j];
        }
        __syncthreads();
    }

    #pragma unroll
    for (int i = 0; i < 4; ++i) {
        int r = rb + ty*4 + i;
        int b_ = r / Nn;
        int n  = r - b_*Nn;
        #pragma unroll
        for (int j = 0; j < 4; ++j) {
            int c = cb + tx*4 + j;
            int which = c / DIMn;           // 0:q 1:k 2:v
            int cc = c - which*DIMn;
            int h  = cc >> 8;               // /256
            int hd = cc & 255;
            int bh = b_*Hn + h;
            float val = acc[i][j];
            if (which == 0)      q[((size_t)bh*Nn + n)*HDn + hd] = val;
            else if (which == 1) k[((size_t)bh*Nn + n)*HDn + hd] = val;
            else                 vcat[((size_t)bh*Nn + n)*Dn + hd] = val;
        }
    }
}

// ---------------------------------------------------------------------------
// K1b: fill positional columns 256..261 of vcat.
// p3[n] = ys[n % 48], p4[n] = xs[n / 48]; ys=linspace(-1,1,48), xs=(-1,1,64)
// ---------------------------------------------------------------------------
__global__ void pos_fill(float* __restrict__ vcat) {
    int idx = blockIdx.x * blockDim.x + threadIdx.x;   // over BH*N
    if (idx >= BHn*Nn) return;
    int n  = idx % Nn;
    int gy = n % 48;
    int gx = n / 48;
    float p3 = -1.0f + (2.0f/47.0f) * gy;
    float p4 = -1.0f + (2.0f/63.0f) * gx;
    float* o = vcat + (size_t)idx*Dn + HDn;
    o[0] = p3*p3; o[1] = p4*p4; o[2] = p3*p4; o[3] = p3; o[4] = p4; o[5] = 1.0f;
}

// ---------------------------------------------------------------------------
// K2: R[n] = sum_m exp(S[n,m]), C[m] = sum_n exp(S[n,m]); S = (q.k^T)*SCALE
// 64x64 S-tile per block, atomicAdd partial sums. R,C pre-zeroed via memset.
// ---------------------------------------------------------------------------
__global__ __launch_bounds__(256) void rc_sums(const float* __restrict__ q,
                                               const float* __restrict__ k,
                                               float* __restrict__ R,
                                               float* __restrict__ C) {
    __shared__ float Qs[16][68];
    __shared__ float Ks[16][68];
    __shared__ float rbuf[64][17];
    __shared__ float cbuf[64][17];
    int tid = threadIdx.x;
    int bh = blockIdx.z;
    int nb = blockIdx.y * 64, mb = blockIdx.x * 64;
    const float* qp = q + (size_t)bh*Nn*HDn;
    const float* kp = k + (size_t)bh*Nn*HDn;
    int lr = tid >> 2, lk = (tid & 3) << 2;
    int ty = tid >> 4, tx = tid & 15;
    float acc[4][4] = {};

    for (int k0 = 0; k0 < HDn; k0 += 16) {
        float4 av = *(const float4*)(qp + (size_t)(nb+lr)*HDn + k0 + lk);
        float4 bv = *(const float4*)(kp + (size_t)(mb+lr)*HDn + k0 + lk);
        Qs[lk+0][lr]=av.x; Qs[lk+1][lr]=av.y; Qs[lk+2][lr]=av.z; Qs[lk+3][lr]=av.w;
        Ks[lk+0][lr]=bv.x; Ks[lk+1][lr]=bv.y; Ks[lk+2][lr]=bv.z; Ks[lk+3][lr]=bv.w;
        __syncthreads();
        #pragma unroll
        for (int kk = 0; kk < 16; ++kk) {
            float a[4], b[4];
            #pragma unroll
            for (int i = 0; i < 4; ++i) a[i] = Qs[kk][ty*4+i];
            #pragma unroll
            for (int j = 0; j < 4; ++j) b[j] = Ks[kk][tx*4+j];
            #pragma unroll
            for (int i = 0; i < 4; ++i)
                #pragma unroll
                for (int j = 0; j < 4; ++j) acc[i][j] += a[i]*b[j];
        }
        __syncthreads();
    }

    float rs[4] = {0,0,0,0}, cs[4] = {0,0,0,0};
    #pragma unroll
    for (int i = 0; i < 4; ++i)
        #pragma unroll
        for (int j = 0; j < 4; ++j) {
            float e = __expf(acc[i][j]*SCALE);
            rs[i] += e; cs[j] += e;
        }
    #pragma unroll
    for (int i = 0; i < 4; ++i) rbuf[ty*4+i][tx] = rs[i];
    #pragma unroll
    for (int j = 0; j < 4; ++j) cbuf[tx*4+j][ty] = cs[j];
    __syncthreads();
    if (tid < 64) {
        float s = 0.f, s2 = 0.f;
        #pragma unroll
        for (int t = 0; t < 16; ++t) { s += rbuf[tid][t]; s2 += cbuf[tid][t]; }
        atomicAdd(&R[(size_t)bh*Nn + nb + tid], s);
        atomicAdd(&C[(size_t)bh*Nn + mb + tid], s2);
    }
}

// ---------------------------------------------------------------------------
// K3: f1a[n,e] = sum_m P[n,m] * vcat[m,e],  P = exp(2S)/(R[n]C[m])
// Flash-style: 32-row n-tile per block, q tile resident in LDS, loop m-chunks
// of 32 recomputing S; all 262 e-columns accumulated in registers.
// ---------------------------------------------------------------------------
__global__ __launch_bounds__(256) void f1a_kernel(const float* __restrict__ q,
                                                  const float* __restrict__ k,
                                                  const float* __restrict__ vcat,
                                                  const float* __restrict__ R,
                                                  const float* __restrict__ C,
                                                  float* __restrict__ f1a) {
    __shared__ float Qs[256][34];     // [kk][n_local] — resident for whole block
    __shared__ float Ks[32][34];      // [kk][m_local] per k-subchunk
    __shared__ float Ps[32][34];      // [n_local][m_local]
    __shared__ float Vs[32][272];     // [m_local][e] (cols >= 262 zero)
    __shared__ float invR[32];
    __shared__ float invC[32];
    int tid = threadIdx.x;
    int n0 = blockIdx.x * 32;
    int bh = blockIdx.y;
    const float* qp = q    + (size_t)bh*Nn*HDn + (size_t)n0*HDn;
    const float* kp = k    + (size_t)bh*Nn*HDn;
    const float* vp = vcat + (size_t)bh*Nn*Dn;

    for (int idx = tid; idx < 32*256; idx += 256) {
        int nl = idx >> 8, kk = idx & 255;
        Qs[kk][nl] = qp[(size_t)nl*HDn + kk];
    }
    if (tid < 32) invR[tid] = 1.0f / R[(size_t)bh*Nn + n0 + tid];

    int ty = tid >> 4, tx = tid & 15;        // phase A: 2x2 of 32x32 S tile
    int np = tid & 15, eg = tid >> 4;        // phase C: 2 rows x 17 cols
    int mrow = tid >> 3, kq = (tid & 7) << 2;

    float acc0[17], acc1[17];
    #pragma unroll
    for (int c = 0; c < 17; ++c) { acc0[c] = 0.f; acc1[c] = 0.f; }

    for (int mc = 0; mc < Nn/32; ++mc) {
        int m0 = mc*32;
        __syncthreads();   // previous iteration's Ps/Vs/invC readers done
        if (tid < 32) invC[tid] = 1.0f / C[(size_t)bh*Nn + m0 + tid];
        for (int idx = tid; idx < 32*272; idx += 256) {
            int r = idx / 272, c = idx - r*272;
            Vs[r][c] = (c < Dn) ? vp[(size_t)(m0 + r)*Dn + c] : 0.0f;
        }
        float s00=0.f, s01=0.f, s10=0.f, s11=0.f;
        for (int ks = 0; ks < 8; ++ks) {
            __syncthreads();
            float4 kv = *(const float4*)(kp + (size_t)(m0 + mrow)*HDn + ks*32 + kq);
            Ks[kq+0][mrow]=kv.x; Ks[kq+1][mrow]=kv.y; Ks[kq+2][mrow]=kv.z; Ks[kq+3][mrow]=kv.w;
            __syncthreads();
            #pragma unroll
            for (int kk = 0; kk < 32; ++kk) {
                float q0 = Qs[ks*32+kk][ty*2+0], q1 = Qs[ks*32+kk][ty*2+1];
                float kv0 = Ks[kk][tx*2+0],      kv1 = Ks[kk][tx*2+1];
                s00 += q0*kv0; s01 += q0*kv1; s10 += q1*kv0; s11 += q1*kv1;
            }
        }
        // P = exp(2*S) * invR * invC ; S = raw*SCALE -> exp(raw*0.125)
        float ir0 = invR[ty*2+0], ir1 = invR[ty*2+1];
        float ic0 = invC[tx*2+0], ic1 = invC[tx*2+1];
        Ps[ty*2+0][tx*2+0] = __expf(0.125f*s00) * ir0 * ic0;
        Ps[ty*2+0][tx*2+1] = __expf(0.125f*s01) * ir0 * ic1;
        Ps[ty*2+1][tx*2+0] = __expf(0.125f*s10) * ir1 * ic0;
        Ps[ty*2+1][tx*2+1] = __expf(0.125f*s11) * ir1 * ic1;
        __syncthreads();
        #pragma unroll 4
        for (int mm = 0; mm < 32; ++mm) {
            float p0 = Ps[np*2+0][mm], p1 = Ps[np*2+1][mm];
            #pragma unroll
            for (int c = 0; c < 17; ++c) {
                float vv = Vs[mm][eg*17 + c];
                acc0[c] += p0*vv;
                acc1[c] += p1*vv;
            }
        }
    }

    #pragma unroll
    for (int c = 0; c < 17; ++c) {
        int e = eg*17 + c;
        if (e < Dn) {
            f1a[((size_t)bh*Nn + n0 + np*2+0)*Dn + e] = acc0[c];
            f1a[((size_t)bh*Nn + n0 + np*2+1)*Dn + e] = acc1[c];
        }
    }
}

// ---------------------------------------------------------------------------
// K4: fund[d,e] = sum_n vcat[n,d] * f1a[n,e]   ([262x3072]@[3072x262] per bh)
// ---------------------------------------------------------------------------
__global__ __launch_bounds__(256) void fund_gemm(const float* __restrict__ vcat,
                                                 const float* __restrict__ f1a,
                                                 float* __restrict__ fund) {
    __shared__ float As[16][68];
    __shared__ float Bs[16][68];
    int tid = threadIdx.x;
    int bh = blockIdx.z;
    int db = blockIdx.y * 64, eb = blockIdx.x * 64;
    const float* vp = vcat + (size_t)bh*Nn*Dn;
    const float* fp = f1a  + (size_t)bh*Nn*Dn;
    int rowk = tid >> 4, c4 = (tid & 15) << 2;
    int ty = tid >> 4, tx = tid & 15;
    float acc[4][4] = {};

    for (int nc = 0; nc < Nn; nc += 16) {
        #pragma unroll
        for (int jj = 0; jj < 4; ++jj) {
            int dd = db + c4 + jj;
            As[rowk][c4+jj] = (dd < Dn) ? vp[(size_t)(nc+rowk)*Dn + dd] : 0.0f;
            int ee = eb + c4 + jj;
            Bs[rowk][c4+jj] = (ee < Dn) ? fp[(size_t)(nc+rowk)*Dn + ee] : 0.0f;
        }
        __syncthreads();
        #pragma unroll
        for (int kk = 0; kk < 16; ++kk) {
            float a[4], b[4];
            #pragma unroll
            for (int i = 0; i < 4; ++i) a[i] = As[kk][ty*4+i];
            #pragma unroll
            for (int j = 0; j < 4; ++j) b[j] = Bs[kk][tx*4+j];
            #pragma unroll
            for (int i = 0; i < 4; ++i)
                #pragma unroll
                for (int j = 0; j < 4; ++j) acc[i][j] += a[i]*b[j];
        }
        __syncthreads();
    }
    #pragma unroll
    for (int i = 0; i < 4; ++i) {
        int d = db + ty*4 + i;
        if (d >= Dn) continue;
        #pragma unroll
        for (int j = 0; j < 4; ++j) {
            int e = eb + tx*4 + j;
            if (e < Dn) fund[(size_t)bh*Dn*Dn + (size_t)d*Dn + e] = acc[i][j];
        }
    }
}

// ---------------------------------------------------------------------------
// K5: out[b,d2,o] = sum_{h,d1} fund[b,h,d1,d2] * W_pf[o, h*262+d1] + b_pf[o]
// ---------------------------------------------------------------------------
__global__ __launch_bounds__(256) void out_gemm(const float* __restrict__ fund,
                                                const float* __restrict__ Wpf,
                                                const float* __restrict__ bpf,
                                                float* __restrict__ out) {
    __shared__ float As[16][68];
    __shared__ float Bs[16][68];
    int tid = threadIdx.x;
    int b_ = blockIdx.z;
    int d2b = blockIdx.y * 64, ob = blockIdx.x * 64;
    int ty = tid >> 4, tx = tid & 15;
    int arow = tid >> 4, ac4 = (tid & 15) << 2;
    int brow = tid >> 2, bj4 = (tid & 3) << 2;
    float acc[4][4] = {};

    for (int jc = 0; jc < 786; jc += 16) {
        int j = jc + arow;
        int h  = j / Dn;
        int d1 = j - h*Dn;
        #pragma unroll
        for (int jj = 0; jj < 4; ++jj) {
            int d2 = d2b + ac4 + jj;
            float v = 0.0f;
            if (j < 786 && d2 < Dn)
                v = fund[((size_t)(b_*Hn + h)*Dn + d1)*Dn + d2];
            As[arow][ac4+jj] = v;
        }
        #pragma unroll
        for (int jj = 0; jj < 4; ++jj) {
            int j2 = jc + bj4 + jj;
            Bs[bj4+jj][brow] = (j2 < 786) ? Wpf[(size_t)(ob + brow)*786 + j2] : 0.0f;
        }
        __syncthreads();
        #pragma unroll
        for (int kk = 0; kk < 16; ++kk) {
            float a[4], b[4];
            #pragma unroll
            for (int i = 0; i < 4; ++i) a[i] = As[kk][ty*4+i];
            #pragma unroll
            for (int j2 = 0; j2 < 4; ++j2) b[j2] = Bs[kk][tx*4+j2];
            #pragma unroll
            for (int i = 0; i < 4; ++i)
                #pragma unroll
                for (int j2 = 0; j2 < 4; ++j2) acc[i][j2] += a[i]*b[j2];
        }
        __syncthreads();
    }
    #pragma unroll
    for (int i = 0; i < 4; ++i) {
        int d2 = d2b + ty*4 + i;
        if (d2 >= Dn) continue;
        #pragma unroll
        for (int j = 0; j < 4; ++j) {
            int o = ob + tx*4 + j;
            out[((size_t)b_*Dn + d2)*DIMn + o] = acc[i][j] + bpf[o];
        }
    }
}

// ---------------------------------------------------------------------------
extern "C" void kernel_launch(void* const* d_in, const int* in_sizes, int n_in,
                              void* d_out, int out_size, void* d_ws, size_t ws_size,
                              hipStream_t stream) {
    const float* x    = (const float*)d_in[0];   // [4,3072,768]
    const float* Wqkv = (const float*)d_in[1];   // [2304,768]
    const float* Wpf  = (const float*)d_in[2];   // [768,786]
    const float* bpf  = (const float*)d_in[3];   // [768]
    float* out = (float*)d_out;                  // [4,262,768]

    float* ws   = (float*)d_ws;
    float* q    = ws;                                  // 12*3072*256
    float* k    = q    + (size_t)BHn*Nn*HDn;           // 12*3072*256
    float* vcat = k    + (size_t)BHn*Nn*HDn;           // 12*3072*262
    float* R    = vcat + (size_t)BHn*Nn*Dn;            // 12*3072
    float* Cc   = R    + (size_t)BHn*Nn;               // 12*3072
    float* f1a  = Cc   + (size_t)BHn*Nn;               // 12*3072*262
    float* fund = f1a  + (size_t)BHn*Nn*Dn;            // 12*262*262
    // total ~156.4 MB of workspace

    hipMemsetAsync(R, 0, (size_t)2*BHn*Nn*sizeof(float), stream);

    qkv_gemm <<<dim3(2304/64, (Bn*Nn)/64), 256, 0, stream>>>(x, Wqkv, q, k, vcat);
    pos_fill <<<dim3((BHn*Nn + 255)/256), 256, 0, stream>>>(vcat);
    rc_sums  <<<dim3(Nn/64, Nn/64, BHn), 256, 0, stream>>>(q, k, R, Cc);
    f1a_kernel<<<dim3(Nn/32, BHn), 256, 0, stream>>>(q, k, vcat, R, Cc, f1a);
    fund_gemm<<<dim3(5, 5, BHn), 256, 0, stream>>>(vcat, f1a, fund);
    out_gemm <<<dim3(DIMn/64, 5, Bn), 256, 0, stream>>>(fund, Wpf, bpf, out);
}

// Round 2
// 2392.132 us; speedup vs baseline: 3.2485x; 3.2485x over previous
//
#include <hip/hip_runtime.h>

typedef unsigned short u16;
typedef u16 u16x8 __attribute__((ext_vector_type(8)));
typedef u16 u16x4 __attribute__((ext_vector_type(4)));
typedef __bf16 bf16x8 __attribute__((ext_vector_type(8)));
typedef float f32x4 __attribute__((ext_vector_type(4)));

#define Bn   4
#define Nn   3072
#define DIMn 768
#define Hn   3
#define HDn  256
#define BHn  12
#define Dn   262
#define EP   272      // e-rows padded to 17*16

__device__ __forceinline__ u16 f2bf(float f) {
    unsigned u = __builtin_bit_cast(unsigned, f);
    u += 0x7fffu + ((u >> 16) & 1u);
    return (u16)(u >> 16);
}
__device__ __forceinline__ float bf2f(u16 h) {
    unsigned u = ((unsigned)h) << 16;
    return __builtin_bit_cast(float, u);
}
__device__ __forceinline__ bf16x8 ld_frag16(const u16* p) {   // 16B-aligned LDS read
    return *(const bf16x8*)p;
}
__device__ __forceinline__ bf16x8 ld_frag8(const u16* p) {    // 8B-aligned (2x b64)
    union { u16x4 h[2]; bf16x8 v; } u;
    u.h[0] = *(const u16x4*)p;
    u.h[1] = *(const u16x4*)(p + 4);
    return u.v;
}
#define MFMA(a,b,c) __builtin_amdgcn_mfma_f32_16x16x32_bf16(a, b, c, 0, 0, 0)

// ---------------------------------------------------------------------------
// K1: qkv = x @ W_qkv^T via MFMA. Writes qh/kh bf16 [bh][n][256] and
// vT bf16 [bh][272][3072] (v transposed; rows 256..271 filled by pos_fill).
// ---------------------------------------------------------------------------
__global__ __launch_bounds__(256) void qkv_mfma(const float* __restrict__ x,
                                                const float* __restrict__ W,
                                                u16* __restrict__ qh,
                                                u16* __restrict__ kh,
                                                u16* __restrict__ vT) {
    __shared__ u16 Xs[64*72];
    __shared__ u16 Ws[64*72];
    __shared__ u16 Cs[64*72];
    int tid = threadIdx.x;
    int w = tid >> 6, lane = tid & 63, quad = lane >> 4, l15 = lane & 15;
    int cb = blockIdx.x, rb = blockIdx.y;
    int r0 = rb * 64;
    int b_ = rb / 48;
    int n0 = (rb % 48) * 64;
    int which = cb / 12;             // 0:q 1:k 2:v
    int c0l = (cb % 12) * 64;        // col base within 768
    int h = c0l >> 8, hd0 = c0l & 255;
    int bh = b_ * Hn + h;
    int wr = w >> 1, wc = w & 1;

    f32x4 acc[2][2];
    #pragma unroll
    for (int i = 0; i < 2; ++i)
        #pragma unroll
        for (int j = 0; j < 2; ++j) acc[i][j] = (f32x4){0.f,0.f,0.f,0.f};

    for (int k0 = 0; k0 < DIMn; k0 += 64) {
        __syncthreads();
        #pragma unroll
        for (int i = 0; i < 4; ++i) {
            int e = tid + i*256;
            int row = e >> 4, c4 = (e & 15) * 4;
            float4 xv = *(const float4*)(x + (size_t)(r0 + row)*DIMn + k0 + c4);
            float4 wv = *(const float4*)(W + (size_t)(which*768 + c0l + row)*DIMn + k0 + c4);
            u16x4 xp, wp;
            xp[0]=f2bf(xv.x); xp[1]=f2bf(xv.y); xp[2]=f2bf(xv.z); xp[3]=f2bf(xv.w);
            wp[0]=f2bf(wv.x); wp[1]=f2bf(wv.y); wp[2]=f2bf(wv.z); wp[3]=f2bf(wv.w);
            *(u16x4*)&Xs[row*72 + c4] = xp;
            *(u16x4*)&Ws[row*72 + c4] = wp;
        }
        __syncthreads();
        #pragma unroll
        for (int ks = 0; ks < 2; ++ks) {
            bf16x8 a0 = ld_frag16(&Xs[(wr*32 +  0 + l15)*72 + ks*32 + quad*8]);
            bf16x8 a1 = ld_frag16(&Xs[(wr*32 + 16 + l15)*72 + ks*32 + quad*8]);
            bf16x8 b0 = ld_frag16(&Ws[(wc*32 +  0 + l15)*72 + ks*32 + quad*8]);
            bf16x8 b1 = ld_frag16(&Ws[(wc*32 + 16 + l15)*72 + ks*32 + quad*8]);
            acc[0][0] = MFMA(a0, b0, acc[0][0]);
            acc[0][1] = MFMA(a0, b1, acc[0][1]);
            acc[1][0] = MFMA(a1, b0, acc[1][0]);
            acc[1][1] = MFMA(a1, b1, acc[1][1]);
        }
    }
    __syncthreads();
    // write C tiles to Cs (transposed for v)
    #pragma unroll
    for (int rt = 0; rt < 2; ++rt)
        #pragma unroll
        for (int ct = 0; ct < 2; ++ct)
            #pragma unroll
            for (int r = 0; r < 4; ++r) {
                int row = wr*32 + rt*16 + quad*4 + r;
                int col = wc*32 + ct*16 + l15;
                u16 v = f2bf(acc[rt][ct][r]);
                if (which < 2) Cs[row*72 + col] = v;
                else           Cs[col*72 + row] = v;
            }
    __syncthreads();
    #pragma unroll
    for (int i = 0; i < 2; ++i) {
        int u = tid + i*256;
        int row = u >> 3, seg = u & 7;
        u16x8 vv = *(const u16x8*)&Cs[row*72 + seg*8];
        if (which == 0)
            *(u16x8*)(qh + ((size_t)bh*Nn + n0 + row)*HDn + hd0 + seg*8) = vv;
        else if (which == 1)
            *(u16x8*)(kh + ((size_t)bh*Nn + n0 + row)*HDn + hd0 + seg*8) = vv;
        else
            *(u16x8*)(vT + ((size_t)bh*EP + hd0 + row)*Nn + n0 + seg*8) = vv;
    }
}

// ---------------------------------------------------------------------------
// K1b: positional rows 256..261 of vT; zero rows 262..271.
// ---------------------------------------------------------------------------
__global__ void pos_fill(u16* __restrict__ vT) {
    int idx = blockIdx.x * blockDim.x + threadIdx.x;   // over BH*16*N
    int bh = idx / (16*Nn);
    int rem = idx - bh*16*Nn;
    int row = rem / Nn;        // 0..15
    int n = rem - row*Nn;
    int gy = n % 48, gx = n / 48;
    float p3 = -1.0f + (2.0f/47.0f)*gy;
    float p4 = -1.0f + (2.0f/63.0f)*gx;
    float v = 0.f;
    if (row == 0) v = p3*p3;
    else if (row == 1) v = p4*p4;
    else if (row == 2) v = p3*p4;
    else if (row == 3) v = p3;
    else if (row == 4) v = p4;
    else if (row == 5) v = 1.0f;
    vT[((size_t)bh*EP + 256 + row)*Nn + n] = f2bf(v);
}

// ---------------------------------------------------------------------------
// K2: R[n]=sum_m exp(S), C[m]=sum_n exp(S), S^T=K·Q^T via MFMA (64x64 tiles).
// ---------------------------------------------------------------------------
__global__ __launch_bounds__(256) void rc_mfma(const u16* __restrict__ qh,
                                               const u16* __restrict__ kh,
                                               float* __restrict__ R,
                                               float* __restrict__ C) {
    __shared__ u16 Qs[64*264];
    __shared__ u16 Ks[64*264];
    int tid = threadIdx.x;
    int w = tid >> 6, lane = tid & 63, quad = lane >> 4, l15 = lane & 15;
    int bh = blockIdx.z;
    int mb = blockIdx.x * 64, nb = blockIdx.y * 64;
    const u16* qp = qh + ((size_t)bh*Nn + nb)*HDn;
    const u16* kp = kh + ((size_t)bh*Nn + mb)*HDn;
    #pragma unroll
    for (int i = 0; i < 8; ++i) {
        int e = tid + i*256;
        int row = e >> 5, seg = e & 31;
        *(u16x8*)&Qs[row*264 + seg*8] = *(const u16x8*)(qp + (size_t)row*HDn + seg*8);
        *(u16x8*)&Ks[row*264 + seg*8] = *(const u16x8*)(kp + (size_t)row*HDn + seg*8);
    }
    __syncthreads();
    int wm = w & 1, wn = w >> 1;
    f32x4 sacc[2][2];
    #pragma unroll
    for (int i = 0; i < 2; ++i)
        #pragma unroll
        for (int j = 0; j < 2; ++j) sacc[i][j] = (f32x4){0.f,0.f,0.f,0.f};
    #pragma unroll
    for (int ks = 0; ks < 8; ++ks) {
        bf16x8 a0 = ld_frag16(&Ks[((2*wm+0)*16 + l15)*264 + ks*32 + quad*8]);
        bf16x8 a1 = ld_frag16(&Ks[((2*wm+1)*16 + l15)*264 + ks*32 + quad*8]);
        bf16x8 b0 = ld_frag16(&Qs[((2*wn+0)*16 + l15)*264 + ks*32 + quad*8]);
        bf16x8 b1 = ld_frag16(&Qs[((2*wn+1)*16 + l15)*264 + ks*32 + quad*8]);
        sacc[0][0] = MFMA(a0, b0, sacc[0][0]);
        sacc[0][1] = MFMA(a0, b1, sacc[0][1]);
        sacc[1][0] = MFMA(a1, b0, sacc[1][0]);
        sacc[1][1] = MFMA(a1, b1, sacc[1][1]);
    }
    float ex[2][2][4];
    #pragma unroll
    for (int mt = 0; mt < 2; ++mt)
        #pragma unroll
        for (int nt = 0; nt < 2; ++nt)
            #pragma unroll
            for (int r = 0; r < 4; ++r)
                ex[mt][nt][r] = __expf(0.0625f * sacc[mt][nt][r]);
    // R: sum over m (rows = quad,r,mt); n fixed per nt
    #pragma unroll
    for (int nt = 0; nt < 2; ++nt) {
        float rp = 0.f;
        #pragma unroll
        for (int mt = 0; mt < 2; ++mt)
            #pragma unroll
            for (int r = 0; r < 4; ++r) rp += ex[mt][nt][r];
        rp += __shfl_xor(rp, 16, 64);
        rp += __shfl_xor(rp, 32, 64);
        if (quad == 0)
            atomicAdd(&R[(size_t)bh*Nn + nb + (2*wn+nt)*16 + l15], rp);
    }
    // C: sum over n (cols = l15, nt); m fixed per (mt, r)
    #pragma unroll
    for (int mt = 0; mt < 2; ++mt)
        #pragma unroll
        for (int r = 0; r < 4; ++r) {
            float cp = ex[mt][0][r] + ex[mt][1][r];
            cp += __shfl_xor(cp, 1, 16);
            cp += __shfl_xor(cp, 2, 16);
            cp += __shfl_xor(cp, 4, 16);
            cp += __shfl_xor(cp, 8, 16);
            if (l15 == 0)
                atomicAdd(&C[(size_t)bh*Nn + mb + (2*wm+mt)*16 + quad*4 + r], cp);
        }
}

// ---------------------------------------------------------------------------
// K2b: invR = 1/R, invC = 1/C
// ---------------------------------------------------------------------------
__global__ void inv_kernel(const float* __restrict__ R, const float* __restrict__ C,
                           float* __restrict__ iR, float* __restrict__ iC) {
    int i = blockIdx.x * blockDim.x + threadIdx.x;
    iR[i] = 1.0f / R[i];
    iC[i] = 1.0f / C[i];
}

// ---------------------------------------------------------------------------
// K2c: vTs[e][m] = vT[e][m] * invC[m]  (bf16, per bh)
// ---------------------------------------------------------------------------
__global__ void scale_v(const u16* __restrict__ vT, const float* __restrict__ iC,
                        u16* __restrict__ vTs) {
    int u = blockIdx.x * blockDim.x + threadIdx.x;     // BH*272*3072/8 units
    int rowg = u / 384;            // bh*272 + e
    int seg = u - rowg*384;
    int bh = rowg / EP;
    size_t off = (size_t)rowg*Nn + seg*8;
    u16x8 in = *(const u16x8*)(vT + off);
    const float4* icp = (const float4*)(iC + (size_t)bh*Nn + seg*8);
    float4 c0 = icp[0], c1 = icp[1];
    u16x8 o;
    o[0]=f2bf(bf2f(in[0])*c0.x); o[1]=f2bf(bf2f(in[1])*c0.y);
    o[2]=f2bf(bf2f(in[2])*c0.z); o[3]=f2bf(bf2f(in[3])*c0.w);
    o[4]=f2bf(bf2f(in[4])*c1.x); o[5]=f2bf(bf2f(in[5])*c1.y);
    o[6]=f2bf(bf2f(in[6])*c1.z); o[7]=f2bf(bf2f(in[7])*c1.w);
    *(u16x8*)(vTs + off) = o;
}

// ---------------------------------------------------------------------------
// K3: f1a[n,e] = invR[n] * sum_m exp(0.125*raw(n,m)) * vTs[e][m]
// n-tile 64/block; m-chunks of 64; S^T=K·Q^T via MFMA; Q-frags in registers;
// P packed bf16 into Ps[n][m] (m-contig) -> A-operand of P·V MFMA.
// ---------------------------------------------------------------------------
__global__ __launch_bounds__(256, 2) void f1a_mfma(const u16* __restrict__ qh,
                                                   const u16* __restrict__ kh,
                                                   const u16* __restrict__ vTs,
                                                   const float* __restrict__ iR,
                                                   float* __restrict__ f1a) {
    __shared__ u16 Ks[64*264];                  // 33792 B
    __shared__ u16 Bpool[EP*72 + 64*68];        // Vt(19584) + Ps(4352) = 47872 B
    u16* Vt = Bpool;
    u16* Ps = Bpool + EP*72;
    u16* Qs = Bpool;                            // overlay during preload
    int tid = threadIdx.x;
    int w = tid >> 6, lane = tid & 63, quad = lane >> 4, l15 = lane & 15;
    int bh = blockIdx.y, n0 = blockIdx.x * 64;
    const u16* qp = qh + ((size_t)bh*Nn + n0)*HDn;
    const u16* kp = kh + (size_t)bh*Nn*HDn;
    const u16* vp = vTs + (size_t)bh*EP*Nn;
    int wm = w & 1, wn = w >> 1;

    // stage Q tile and preload Q-fragments (B-operand of S^T) into registers
    #pragma unroll
    for (int i = 0; i < 8; ++i) {
        int e = tid + i*256;
        int row = e >> 5, seg = e & 31;
        *(u16x8*)&Qs[row*264 + seg*8] = *(const u16x8*)(qp + (size_t)row*HDn + seg*8);
    }
    __syncthreads();
    bf16x8 qf[2][8];
    #pragma unroll
    for (int nt = 0; nt < 2; ++nt)
        #pragma unroll
        for (int ks = 0; ks < 8; ++ks)
            qf[nt][ks] = ld_frag16(&Qs[((2*wn+nt)*16 + l15)*264 + ks*32 + quad*8]);

    int et0 = w*4;
    int etc = (w == 3) ? 5 : 4;
    f32x4 acc[4][5];
    #pragma unroll
    for (int a = 0; a < 4; ++a)
        #pragma unroll
        for (int b = 0; b < 5; ++b) acc[a][b] = (f32x4){0.f,0.f,0.f,0.f};

    for (int mc = 0; mc < Nn/64; ++mc) {
        int m0 = mc * 64;
        __syncthreads();   // prev PV readers (Vt/Ps) done; Qs preload done (mc=0)
        // stage K tile [64][256]
        #pragma unroll
        for (int i = 0; i < 8; ++i) {
            int e = tid + i*256;
            int row = e >> 5, seg = e & 31;
            *(u16x8*)&Ks[row*264 + seg*8] =
                *(const u16x8*)(kp + (size_t)(m0 + row)*HDn + seg*8);
        }
        // stage Vt [272][64] (already scaled by invC)
        for (int u = tid; u < EP*8; u += 256) {
            int row = u >> 3, seg = u & 7;
            *(u16x8*)&Vt[row*72 + seg*8] =
                *(const u16x8*)(vp + (size_t)row*Nn + m0 + seg*8);
        }
        __syncthreads();
        // S^T = K·Q^T  (C rows = m, cols = n)
        f32x4 sacc[2][2];
        #pragma unroll
        for (int i = 0; i < 2; ++i)
            #pragma unroll
            for (int j = 0; j < 2; ++j) sacc[i][j] = (f32x4){0.f,0.f,0.f,0.f};
        #pragma unroll
        for (int ks = 0; ks < 8; ++ks) {
            bf16x8 a0 = ld_frag16(&Ks[((2*wm+0)*16 + l15)*264 + ks*32 + quad*8]);
            bf16x8 a1 = ld_frag16(&Ks[((2*wm+1)*16 + l15)*264 + ks*32 + quad*8]);
            sacc[0][0] = MFMA(a0, qf[0][ks], sacc[0][0]);
            sacc[0][1] = MFMA(a0, qf[1][ks], sacc[0][1]);
            sacc[1][0] = MFMA(a1, qf[0][ks], sacc[1][0]);
            sacc[1][1] = MFMA(a1, qf[1][ks], sacc[1][1]);
        }
        // P = exp(2*S) = exp(0.125*raw); pack 4 m-contig bf16, write Ps[n][m]
        #pragma unroll
        for (int mt = 0; mt < 2; ++mt)
            #pragma unroll
            for (int nt = 0; nt < 2; ++nt) {
                u16x4 pk;
                #pragma unroll
                for (int r = 0; r < 4; ++r)
                    pk[r] = f2bf(__expf(0.125f * sacc[mt][nt][r]));
                int n = (2*wn+nt)*16 + l15;
                int m = (2*wm+mt)*16 + quad*4;
                *(u16x4*)&Ps[n*68 + m] = pk;
            }
        __syncthreads();
        // PV: f1a_tile += P · V   (A = Ps[n][m], B = Vt[e][m])
        #pragma unroll
        for (int ks = 0; ks < 2; ++ks) {
            bf16x8 pa[4];
            #pragma unroll
            for (int nt = 0; nt < 4; ++nt)
                pa[nt] = ld_frag8(&Ps[(nt*16 + l15)*68 + ks*32 + quad*8]);
            for (int et = 0; et < etc; ++et) {
                bf16x8 vb = ld_frag16(&Vt[((et0+et)*16 + l15)*72 + ks*32 + quad*8]);
                #pragma unroll
                for (int nt = 0; nt < 4; ++nt)
                    acc[nt][et] = MFMA(pa[nt], vb, acc[nt][et]);
            }
        }
    }
    // epilogue: scale by invR[n], store f1a[n][e]
    #pragma unroll
    for (int nt = 0; nt < 4; ++nt)
        #pragma unroll
        for (int r = 0; r < 4; ++r) {
            int n = n0 + nt*16 + quad*4 + r;
            float ir = iR[(size_t)bh*Nn + n];
            for (int et = 0; et < etc; ++et) {
                int e = (et0+et)*16 + l15;
                if (e < Dn)
                    f1a[((size_t)bh*Nn + n)*Dn + e] = acc[nt][et][r] * ir;
            }
        }
}

// ---------------------------------------------------------------------------
// K4: fund[d,e] = sum_n vT[d][n] * f1a[n][e]   (fp32 vector, small)
// ---------------------------------------------------------------------------
__global__ __launch_bounds__(256) void fund_gemm(const u16* __restrict__ vT,
                                                 const float* __restrict__ f1a,
                                                 float* __restrict__ fund) {
    __shared__ float As[16][68];
    __shared__ float Bs[16][68];
    int tid = threadIdx.x;
    int bh = blockIdx.z;
    int db = blockIdx.y * 64, eb = blockIdx.x * 64;
    const u16* vp = vT + (size_t)bh*EP*Nn;
    const float* fp = f1a + (size_t)bh*Nn*Dn;
    int ty = tid >> 4, tx = tid & 15;
    float acc[4][4] = {};

    for (int nc = 0; nc < Nn; nc += 16) {
        {
            int dd = tid >> 2, kk0 = (tid & 3) * 4;
            int d = db + dd;
            if (d < EP) {
                u16x4 a4 = *(const u16x4*)(vp + (size_t)d*Nn + nc + kk0);
                #pragma unroll
                for (int i = 0; i < 4; ++i) As[kk0+i][dd] = bf2f(a4[i]);
            } else {
                #pragma unroll
                for (int i = 0; i < 4; ++i) As[kk0+i][dd] = 0.f;
            }
            int kk = tid >> 4, ee0 = (tid & 15) * 4;
            #pragma unroll
            for (int i = 0; i < 4; ++i) {
                int e = eb + ee0 + i;
                Bs[kk][ee0+i] = (e < Dn) ? fp[(size_t)(nc+kk)*Dn + e] : 0.f;
            }
        }
        __syncthreads();
        #pragma unroll
        for (int kk = 0; kk < 16; ++kk) {
            float a[4], b[4];
            #pragma unroll
            for (int i = 0; i < 4; ++i) a[i] = As[kk][ty*4+i];
            #pragma unroll
            for (int j = 0; j < 4; ++j) b[j] = Bs[kk][tx*4+j];
            #pragma unroll
            for (int i = 0; i < 4; ++i)
                #pragma unroll
                for (int j = 0; j < 4; ++j) acc[i][j] += a[i]*b[j];
        }
        __syncthreads();
    }
    #pragma unroll
    for (int i = 0; i < 4; ++i) {
        int d = db + ty*4 + i;
        if (d >= Dn) continue;
        #pragma unroll
        for (int j = 0; j < 4; ++j) {
            int e = eb + tx*4 + j;
            if (e < Dn) fund[(size_t)bh*Dn*Dn + (size_t)d*Dn + e] = acc[i][j];
        }
    }
}

// ---------------------------------------------------------------------------
// K5: out[b,d2,o] = sum_{h,d1} fund[b,h,d1,d2] * W_pf[o, h*262+d1] + b_pf[o]
// ---------------------------------------------------------------------------
__global__ __launch_bounds__(256) void out_gemm(const float* __restrict__ fund,
                                                const float* __restrict__ Wpf,
                                                const float* __restrict__ bpf,
                                                float* __restrict__ out) {
    __shared__ float As[16][68];
    __shared__ float Bs[16][68];
    int tid = threadIdx.x;
    int b_ = blockIdx.z;
    int d2b = blockIdx.y * 64, ob = blockIdx.x * 64;
    int ty = tid >> 4, tx = tid & 15;
    int arow = tid >> 4, ac4 = (tid & 15) << 2;
    int brow = tid >> 2, bj4 = (tid & 3) << 2;
    float acc[4][4] = {};

    for (int jc = 0; jc < 786; jc += 16) {
        int j = jc + arow;
        int h  = j / Dn;
        int d1 = j - h*Dn;
        #pragma unroll
        for (int jj = 0; jj < 4; ++jj) {
            int d2 = d2b + ac4 + jj;
            float v = 0.0f;
            if (j < 786 && d2 < Dn)
                v = fund[((size_t)(b_*Hn + h)*Dn + d1)*Dn + d2];
            As[arow][ac4+jj] = v;
        }
        #pragma unroll
        for (int jj = 0; jj < 4; ++jj) {
            int j2 = jc + bj4 + jj;
            Bs[bj4+jj][brow] = (j2 < 786) ? Wpf[(size_t)(ob + brow)*786 + j2] : 0.0f;
        }
        __syncthreads();
        #pragma unroll
        for (int kk = 0; kk < 16; ++kk) {
            float a[4], b[4];
            #pragma unroll
            for (int i = 0; i < 4; ++i) a[i] = As[kk][ty*4+i];
            #pragma unroll
            for (int j2 = 0; j2 < 4; ++j2) b[j2] = Bs[kk][tx*4+j2];
            #pragma unroll
            for (int i = 0; i < 4; ++i)
                #pragma unroll
                for (int j2 = 0; j2 < 4; ++j2) acc[i][j2] += a[i]*b[j2];
        }
        __syncthreads();
    }
    #pragma unroll
    for (int i = 0; i < 4; ++i) {
        int d2 = d2b + ty*4 + i;
        if (d2 >= Dn) continue;
        #pragma unroll
        for (int j = 0; j < 4; ++j) {
            int o = ob + tx*4 + j;
            out[((size_t)b_*Dn + d2)*DIMn + o] = acc[i][j] + bpf[o];
        }
    }
}

// ---------------------------------------------------------------------------
extern "C" void kernel_launch(void* const* d_in, const int* in_sizes, int n_in,
                              void* d_out, int out_size, void* d_ws, size_t ws_size,
                              hipStream_t stream) {
    const float* x    = (const float*)d_in[0];   // [4,3072,768]
    const float* Wqkv = (const float*)d_in[1];   // [2304,768]
    const float* Wpf  = (const float*)d_in[2];   // [768,786]
    const float* bpf  = (const float*)d_in[3];   // [768]
    float* out = (float*)d_out;                  // [4,262,768]

    char* p = (char*)d_ws;
    u16* qh    = (u16*)p;                       p += (size_t)BHn*Nn*HDn*2;   // 18.87 MB
    u16* kh    = (u16*)p;                       p += (size_t)BHn*Nn*HDn*2;   // 18.87 MB
    u16* vT    = (u16*)p;                       p += (size_t)BHn*EP*Nn*2;    // 20.05 MB
    u16* vTs   = (u16*)p;                       p += (size_t)BHn*EP*Nn*2;    // 20.05 MB
    float* R   = (float*)p;                     p += (size_t)BHn*Nn*4;
    float* Cc  = (float*)p;                     p += (size_t)BHn*Nn*4;
    float* iR  = (float*)p;                     p += (size_t)BHn*Nn*4;
    float* iC  = (float*)p;                     p += (size_t)BHn*Nn*4;
    float* f1a = (float*)p;                     p += (size_t)BHn*Nn*Dn*4;    // 38.63 MB
    float* fund= (float*)p;                     p += (size_t)BHn*Dn*Dn*4;    // 3.29 MB

    hipMemsetAsync(R, 0, (size_t)2*BHn*Nn*sizeof(float), stream);

    qkv_mfma <<<dim3(36, 192), 256, 0, stream>>>(x, Wqkv, qh, kh, vT);
    pos_fill <<<dim3(BHn*16*Nn/256), 256, 0, stream>>>(vT);
    rc_mfma  <<<dim3(Nn/64, Nn/64, BHn), 256, 0, stream>>>(qh, kh, R, Cc);
    inv_kernel<<<dim3(BHn*Nn/256), 256, 0, stream>>>(R, Cc, iR, iC);
    scale_v  <<<dim3(BHn*EP*Nn/8/256), 256, 0, stream>>>(vT, iC, vTs);
    f1a_mfma <<<dim3(Nn/64, BHn), 256, 0, stream>>>(qh, kh, vTs, iR, f1a);
    fund_gemm<<<dim3(5, 5, BHn), 256, 0, stream>>>(vT, f1a, fund);
    out_gemm <<<dim3(DIMn/64, 5, Bn), 256, 0, stream>>>(fund, Wpf, bpf, out);
}

// Round 3
// 1458.777 us; speedup vs baseline: 5.3270x; 1.6398x over previous
//
#include <hip/hip_runtime.h>

typedef unsigned short u16;
typedef u16 u16x8 __attribute__((ext_vector_type(8)));
typedef u16 u16x4 __attribute__((ext_vector_type(4)));
typedef __bf16 bf16x8 __attribute__((ext_vector_type(8)));
typedef float f32x4 __attribute__((ext_vector_type(4)));

#define Bn   4
#define Nn   3072
#define DIMn 768
#define Hn   3
#define HDn  256
#define BHn  12
#define Dn   262
#define EP   272      // e-rows padded to 17*16

__device__ __forceinline__ u16 f2bf(float f) {
    unsigned u = __builtin_bit_cast(unsigned, f);
    u += 0x7fffu + ((u >> 16) & 1u);
    return (u16)(u >> 16);
}
__device__ __forceinline__ float bf2f(u16 h) {
    unsigned u = ((unsigned)h) << 16;
    return __builtin_bit_cast(float, u);
}
__device__ __forceinline__ bf16x8 ld_frag16(const u16* p) {   // 16B-aligned LDS read
    return *(const bf16x8*)p;
}
__device__ __forceinline__ bf16x8 ld_frag8(const u16* p) {    // 8B-aligned (2x b64)
    union { u16x4 h[2]; bf16x8 v; } u;
    u.h[0] = *(const u16x4*)p;
    u.h[1] = *(const u16x4*)(p + 4);
    return u.v;
}
#define MFMA(a,b,c) __builtin_amdgcn_mfma_f32_16x16x32_bf16(a, b, c, 0, 0, 0)

// ---------------------------------------------------------------------------
// K1: qkv = x @ W_qkv^T via MFMA. Writes qh/kh bf16 [bh][n][256] and
// vT bf16 [bh][272][3072] (v transposed; rows 256..271 filled by pos_fill).
// ---------------------------------------------------------------------------
__global__ __launch_bounds__(256) void qkv_mfma(const float* __restrict__ x,
                                                const float* __restrict__ W,
                                                u16* __restrict__ qh,
                                                u16* __restrict__ kh,
                                                u16* __restrict__ vT) {
    __shared__ u16 Xs[64*72];
    __shared__ u16 Ws[64*72];
    __shared__ u16 Cs[64*72];
    int tid = threadIdx.x;
    int w = tid >> 6, lane = tid & 63, quad = lane >> 4, l15 = lane & 15;
    int cb = blockIdx.x, rb = blockIdx.y;
    int r0 = rb * 64;
    int b_ = rb / 48;
    int n0 = (rb % 48) * 64;
    int which = cb / 12;             // 0:q 1:k 2:v
    int c0l = (cb % 12) * 64;        // col base within 768
    int h = c0l >> 8, hd0 = c0l & 255;
    int bh = b_ * Hn + h;
    int wr = w >> 1, wc = w & 1;

    f32x4 acc[2][2];
    #pragma unroll
    for (int i = 0; i < 2; ++i)
        #pragma unroll
        for (int j = 0; j < 2; ++j) acc[i][j] = (f32x4){0.f,0.f,0.f,0.f};

    for (int k0 = 0; k0 < DIMn; k0 += 64) {
        __syncthreads();
        #pragma unroll
        for (int i = 0; i < 4; ++i) {
            int e = tid + i*256;
            int row = e >> 4, c4 = (e & 15) * 4;
            float4 xv = *(const float4*)(x + (size_t)(r0 + row)*DIMn + k0 + c4);
            float4 wv = *(const float4*)(W + (size_t)(which*768 + c0l + row)*DIMn + k0 + c4);
            u16x4 xp, wp;
            xp[0]=f2bf(xv.x); xp[1]=f2bf(xv.y); xp[2]=f2bf(xv.z); xp[3]=f2bf(xv.w);
            wp[0]=f2bf(wv.x); wp[1]=f2bf(wv.y); wp[2]=f2bf(wv.z); wp[3]=f2bf(wv.w);
            *(u16x4*)&Xs[row*72 + c4] = xp;
            *(u16x4*)&Ws[row*72 + c4] = wp;
        }
        __syncthreads();
        #pragma unroll
        for (int ks = 0; ks < 2; ++ks) {
            bf16x8 a0 = ld_frag16(&Xs[(wr*32 +  0 + l15)*72 + ks*32 + quad*8]);
            bf16x8 a1 = ld_frag16(&Xs[(wr*32 + 16 + l15)*72 + ks*32 + quad*8]);
            bf16x8 b0 = ld_frag16(&Ws[(wc*32 +  0 + l15)*72 + ks*32 + quad*8]);
            bf16x8 b1 = ld_frag16(&Ws[(wc*32 + 16 + l15)*72 + ks*32 + quad*8]);
            acc[0][0] = MFMA(a0, b0, acc[0][0]);
            acc[0][1] = MFMA(a0, b1, acc[0][1]);
            acc[1][0] = MFMA(a1, b0, acc[1][0]);
            acc[1][1] = MFMA(a1, b1, acc[1][1]);
        }
    }
    __syncthreads();
    // write C tiles to Cs (transposed for v)
    #pragma unroll
    for (int rt = 0; rt < 2; ++rt)
        #pragma unroll
        for (int ct = 0; ct < 2; ++ct)
            #pragma unroll
            for (int r = 0; r < 4; ++r) {
                int row = wr*32 + rt*16 + quad*4 + r;
                int col = wc*32 + ct*16 + l15;
                u16 v = f2bf(acc[rt][ct][r]);
                if (which < 2) Cs[row*72 + col] = v;
                else           Cs[col*72 + row] = v;
            }
    __syncthreads();
    #pragma unroll
    for (int i = 0; i < 2; ++i) {
        int u = tid + i*256;
        int row = u >> 3, seg = u & 7;
        u16x8 vv = *(const u16x8*)&Cs[row*72 + seg*8];
        if (which == 0)
            *(u16x8*)(qh + ((size_t)bh*Nn + n0 + row)*HDn + hd0 + seg*8) = vv;
        else if (which == 1)
            *(u16x8*)(kh + ((size_t)bh*Nn + n0 + row)*HDn + hd0 + seg*8) = vv;
        else
            *(u16x8*)(vT + ((size_t)bh*EP + hd0 + row)*Nn + n0 + seg*8) = vv;
    }
}

// ---------------------------------------------------------------------------
// K1b: positional rows 256..261 of vT; zero rows 262..271.
// ---------------------------------------------------------------------------
__global__ void pos_fill(u16* __restrict__ vT) {
    int idx = blockIdx.x * blockDim.x + threadIdx.x;   // over BH*16*N
    int bh = idx / (16*Nn);
    int rem = idx - bh*16*Nn;
    int row = rem / Nn;        // 0..15
    int n = rem - row*Nn;
    int gy = n % 48, gx = n / 48;
    float p3 = -1.0f + (2.0f/47.0f)*gy;
    float p4 = -1.0f + (2.0f/63.0f)*gx;
    float v = 0.f;
    if (row == 0) v = p3*p3;
    else if (row == 1) v = p4*p4;
    else if (row == 2) v = p3*p4;
    else if (row == 3) v = p3;
    else if (row == 4) v = p4;
    else if (row == 5) v = 1.0f;
    vT[((size_t)bh*EP + 256 + row)*Nn + n] = f2bf(v);
}

// ---------------------------------------------------------------------------
// K2: R[n]=sum_m exp(S), C[m]=sum_n exp(S), S^T=K·Q^T via MFMA (64x64 tiles).
// ---------------------------------------------------------------------------
__global__ __launch_bounds__(256) void rc_mfma(const u16* __restrict__ qh,
                                               const u16* __restrict__ kh,
                                               float* __restrict__ R,
                                               float* __restrict__ C) {
    __shared__ u16 Qs[64*264];
    __shared__ u16 Ks[64*264];
    int tid = threadIdx.x;
    int w = tid >> 6, lane = tid & 63, quad = lane >> 4, l15 = lane & 15;
    int bh = blockIdx.z;
    int mb = blockIdx.x * 64, nb = blockIdx.y * 64;
    const u16* qp = qh + ((size_t)bh*Nn + nb)*HDn;
    const u16* kp = kh + ((size_t)bh*Nn + mb)*HDn;
    #pragma unroll
    for (int i = 0; i < 8; ++i) {
        int e = tid + i*256;
        int row = e >> 5, seg = e & 31;
        *(u16x8*)&Qs[row*264 + seg*8] = *(const u16x8*)(qp + (size_t)row*HDn + seg*8);
        *(u16x8*)&Ks[row*264 + seg*8] = *(const u16x8*)(kp + (size_t)row*HDn + seg*8);
    }
    __syncthreads();
    int wm = w & 1, wn = w >> 1;
    f32x4 sacc[2][2];
    #pragma unroll
    for (int i = 0; i < 2; ++i)
        #pragma unroll
        for (int j = 0; j < 2; ++j) sacc[i][j] = (f32x4){0.f,0.f,0.f,0.f};
    #pragma unroll
    for (int ks = 0; ks < 8; ++ks) {
        bf16x8 a0 = ld_frag16(&Ks[((2*wm+0)*16 + l15)*264 + ks*32 + quad*8]);
        bf16x8 a1 = ld_frag16(&Ks[((2*wm+1)*16 + l15)*264 + ks*32 + quad*8]);
        bf16x8 b0 = ld_frag16(&Qs[((2*wn+0)*16 + l15)*264 + ks*32 + quad*8]);
        bf16x8 b1 = ld_frag16(&Qs[((2*wn+1)*16 + l15)*264 + ks*32 + quad*8]);
        sacc[0][0] = MFMA(a0, b0, sacc[0][0]);
        sacc[0][1] = MFMA(a0, b1, sacc[0][1]);
        sacc[1][0] = MFMA(a1, b0, sacc[1][0]);
        sacc[1][1] = MFMA(a1, b1, sacc[1][1]);
    }
    float ex[2][2][4];
    #pragma unroll
    for (int mt = 0; mt < 2; ++mt)
        #pragma unroll
        for (int nt = 0; nt < 2; ++nt)
            #pragma unroll
            for (int r = 0; r < 4; ++r)
                ex[mt][nt][r] = __expf(0.0625f * sacc[mt][nt][r]);
    // R: sum over m (rows = quad,r,mt); n fixed per nt
    #pragma unroll
    for (int nt = 0; nt < 2; ++nt) {
        float rp = 0.f;
        #pragma unroll
        for (int mt = 0; mt < 2; ++mt)
            #pragma unroll
            for (int r = 0; r < 4; ++r) rp += ex[mt][nt][r];
        rp += __shfl_xor(rp, 16, 64);
        rp += __shfl_xor(rp, 32, 64);
        if (quad == 0)
            atomicAdd(&R[(size_t)bh*Nn + nb + (2*wn+nt)*16 + l15], rp);
    }
    // C: sum over n (cols = l15, nt); m fixed per (mt, r)
    #pragma unroll
    for (int mt = 0; mt < 2; ++mt)
        #pragma unroll
        for (int r = 0; r < 4; ++r) {
            float cp = ex[mt][0][r] + ex[mt][1][r];
            cp += __shfl_xor(cp, 1, 16);
            cp += __shfl_xor(cp, 2, 16);
            cp += __shfl_xor(cp, 4, 16);
            cp += __shfl_xor(cp, 8, 16);
            if (l15 == 0)
                atomicAdd(&C[(size_t)bh*Nn + mb + (2*wm+mt)*16 + quad*4 + r], cp);
        }
}

// ---------------------------------------------------------------------------
// K2b: invR = 1/R, invC = 1/C
// ---------------------------------------------------------------------------
__global__ void inv_kernel(const float* __restrict__ R, const float* __restrict__ C,
                           float* __restrict__ iR, float* __restrict__ iC) {
    int i = blockIdx.x * blockDim.x + threadIdx.x;
    iR[i] = 1.0f / R[i];
    iC[i] = 1.0f / C[i];
}

// ---------------------------------------------------------------------------
// K2c: vTs[e][m] = vT[e][m] * invC[m]  (bf16, per bh)
// ---------------------------------------------------------------------------
__global__ void scale_v(const u16* __restrict__ vT, const float* __restrict__ iC,
                        u16* __restrict__ vTs) {
    int u = blockIdx.x * blockDim.x + threadIdx.x;     // BH*272*3072/8 units
    int rowg = u / 384;            // bh*272 + e
    int seg = u - rowg*384;
    int bh = rowg / EP;
    size_t off = (size_t)rowg*Nn + seg*8;
    u16x8 in = *(const u16x8*)(vT + off);
    const float4* icp = (const float4*)(iC + (size_t)bh*Nn + seg*8);
    float4 c0 = icp[0], c1 = icp[1];
    u16x8 o;
    o[0]=f2bf(bf2f(in[0])*c0.x); o[1]=f2bf(bf2f(in[1])*c0.y);
    o[2]=f2bf(bf2f(in[2])*c0.z); o[3]=f2bf(bf2f(in[3])*c0.w);
    o[4]=f2bf(bf2f(in[4])*c1.x); o[5]=f2bf(bf2f(in[5])*c1.y);
    o[6]=f2bf(bf2f(in[6])*c1.z); o[7]=f2bf(bf2f(in[7])*c1.w);
    *(u16x8*)(vTs + off) = o;
}

// ---------------------------------------------------------------------------
// K3: f1a[n,e] = invR[n] * sum_m exp(0.125*raw(n,m)) * vTs[e][m]
// n-tile 64/block; m-chunks of 64; S^T=K·Q^T via MFMA; Q-frags in registers;
// P packed bf16 into Ps[n][m] (m-contig) -> A-operand of P·V MFMA.
// NOTE: et loops MUST have compile-time trip counts with wave-uniform guards;
// a runtime trip count demotes acc[][] to scratch (3 GB of HBM writes, R2 bug).
// ---------------------------------------------------------------------------
__global__ __launch_bounds__(256, 2) void f1a_mfma(const u16* __restrict__ qh,
                                                   const u16* __restrict__ kh,
                                                   const u16* __restrict__ vTs,
                                                   const float* __restrict__ iR,
                                                   float* __restrict__ f1a) {
    __shared__ u16 Ks[64*264];                  // 33792 B
    __shared__ u16 Bpool[EP*72 + 64*68];        // Vt(39168B) + Ps(8704B)
    u16* Vt = Bpool;
    u16* Ps = Bpool + EP*72;
    u16* Qs = Bpool;                            // overlay during preload
    int tid = threadIdx.x;
    int w = tid >> 6, lane = tid & 63, quad = lane >> 4, l15 = lane & 15;
    int bh = blockIdx.y, n0 = blockIdx.x * 64;
    const u16* qp = qh + ((size_t)bh*Nn + n0)*HDn;
    const u16* kp = kh + (size_t)bh*Nn*HDn;
    const u16* vp = vTs + (size_t)bh*EP*Nn;
    int wm = w & 1, wn = w >> 1;

    // stage Q tile and preload Q-fragments (B-operand of S^T) into registers
    #pragma unroll
    for (int i = 0; i < 8; ++i) {
        int e = tid + i*256;
        int row = e >> 5, seg = e & 31;
        *(u16x8*)&Qs[row*264 + seg*8] = *(const u16x8*)(qp + (size_t)row*HDn + seg*8);
    }
    __syncthreads();
    bf16x8 qf[2][8];
    #pragma unroll
    for (int nt = 0; nt < 2; ++nt)
        #pragma unroll
        for (int ks = 0; ks < 8; ++ks)
            qf[nt][ks] = ld_frag16(&Qs[((2*wn+nt)*16 + l15)*264 + ks*32 + quad*8]);

    const int et0 = w*4;                // wave w owns e-tiles et0..; wave 3 gets 5th
    f32x4 acc[4][5];
    #pragma unroll
    for (int a = 0; a < 4; ++a)
        #pragma unroll
        for (int b = 0; b < 5; ++b) acc[a][b] = (f32x4){0.f,0.f,0.f,0.f};

    for (int mc = 0; mc < Nn/64; ++mc) {
        int m0 = mc * 64;
        __syncthreads();   // prev PV readers (Vt/Ps) done; Qs preload done (mc=0)
        // stage K tile [64][256]
        #pragma unroll
        for (int i = 0; i < 8; ++i) {
            int e = tid + i*256;
            int row = e >> 5, seg = e & 31;
            *(u16x8*)&Ks[row*264 + seg*8] =
                *(const u16x8*)(kp + (size_t)(m0 + row)*HDn + seg*8);
        }
        // stage Vt [272][64] (already scaled by invC)
        for (int u = tid; u < EP*8; u += 256) {
            int row = u >> 3, seg = u & 7;
            *(u16x8*)&Vt[row*72 + seg*8] =
                *(const u16x8*)(vp + (size_t)row*Nn + m0 + seg*8);
        }
        __syncthreads();
        // S^T = K·Q^T  (C rows = m, cols = n)
        f32x4 sacc[2][2];
        #pragma unroll
        for (int i = 0; i < 2; ++i)
            #pragma unroll
            for (int j = 0; j < 2; ++j) sacc[i][j] = (f32x4){0.f,0.f,0.f,0.f};
        #pragma unroll
        for (int ks = 0; ks < 8; ++ks) {
            bf16x8 a0 = ld_frag16(&Ks[((2*wm+0)*16 + l15)*264 + ks*32 + quad*8]);
            bf16x8 a1 = ld_frag16(&Ks[((2*wm+1)*16 + l15)*264 + ks*32 + quad*8]);
            sacc[0][0] = MFMA(a0, qf[0][ks], sacc[0][0]);
            sacc[0][1] = MFMA(a0, qf[1][ks], sacc[0][1]);
            sacc[1][0] = MFMA(a1, qf[0][ks], sacc[1][0]);
            sacc[1][1] = MFMA(a1, qf[1][ks], sacc[1][1]);
        }
        // P = exp(2*S) = exp(0.125*raw); pack 4 m-contig bf16, write Ps[n][m]
        #pragma unroll
        for (int mt = 0; mt < 2; ++mt)
            #pragma unroll
            for (int nt = 0; nt < 2; ++nt) {
                u16x4 pk;
                #pragma unroll
                for (int r = 0; r < 4; ++r)
                    pk[r] = f2bf(__expf(0.125f * sacc[mt][nt][r]));
                int n = (2*wn+nt)*16 + l15;
                int m = (2*wm+mt)*16 + quad*4;
                *(u16x4*)&Ps[n*68 + m] = pk;
            }
        __syncthreads();
        // PV: f1a_tile += P · V   (A = Ps[n][m], B = Vt[e][m])
        #pragma unroll
        for (int ks = 0; ks < 2; ++ks) {
            bf16x8 pa[4];
            #pragma unroll
            for (int nt = 0; nt < 4; ++nt)
                pa[nt] = ld_frag8(&Ps[(nt*16 + l15)*68 + ks*32 + quad*8]);
            #pragma unroll
            for (int et = 0; et < 5; ++et) {
                if (et0 + et < 17) {   // wave-uniform; compile-time indices
                    bf16x8 vb = ld_frag16(&Vt[((et0+et)*16 + l15)*72 + ks*32 + quad*8]);
                    #pragma unroll
                    for (int nt = 0; nt < 4; ++nt)
                        acc[nt][et] = MFMA(pa[nt], vb, acc[nt][et]);
                }
            }
        }
    }
    // epilogue: scale by invR[n], store f1a[n][e]
    #pragma unroll
    for (int nt = 0; nt < 4; ++nt)
        #pragma unroll
        for (int r = 0; r < 4; ++r) {
            int n = n0 + nt*16 + quad*4 + r;
            float ir = iR[(size_t)bh*Nn + n];
            #pragma unroll
            for (int et = 0; et < 5; ++et) {
                if (et0 + et < 17) {
                    int e = (et0+et)*16 + l15;
                    if (e < Dn)
                        f1a[((size_t)bh*Nn + n)*Dn + e] = acc[nt][et][r] * ir;
                }
            }
        }
}

// ---------------------------------------------------------------------------
// K4: fund[d,e] = sum_n vT[d][n] * f1a[n][e]   (fp32 vector, small)
// ---------------------------------------------------------------------------
__global__ __launch_bounds__(256) void fund_gemm(const u16* __restrict__ vT,
                                                 const float* __restrict__ f1a,
                                                 float* __restrict__ fund) {
    __shared__ float As[16][68];
    __shared__ float Bs[16][68];
    int tid = threadIdx.x;
    int bh = blockIdx.z;
    int db = blockIdx.y * 64, eb = blockIdx.x * 64;
    const u16* vp = vT + (size_t)bh*EP*Nn;
    const float* fp = f1a + (size_t)bh*Nn*Dn;
    int ty = tid >> 4, tx = tid & 15;
    float acc[4][4] = {};

    for (int nc = 0; nc < Nn; nc += 16) {
        {
            int dd = tid >> 2, kk0 = (tid & 3) * 4;
            int d = db + dd;
            if (d < EP) {
                u16x4 a4 = *(const u16x4*)(vp + (size_t)d*Nn + nc + kk0);
                #pragma unroll
                for (int i = 0; i < 4; ++i) As[kk0+i][dd] = bf2f(a4[i]);
            } else {
                #pragma unroll
                for (int i = 0; i < 4; ++i) As[kk0+i][dd] = 0.f;
            }
            int kk = tid >> 4, ee0 = (tid & 15) * 4;
            #pragma unroll
            for (int i = 0; i < 4; ++i) {
                int e = eb + ee0 + i;
                Bs[kk][ee0+i] = (e < Dn) ? fp[(size_t)(nc+kk)*Dn + e] : 0.f;
            }
        }
        __syncthreads();
        #pragma unroll
        for (int kk = 0; kk < 16; ++kk) {
            float a[4], b[4];
            #pragma unroll
            for (int i = 0; i < 4; ++i) a[i] = As[kk][ty*4+i];
            #pragma unroll
            for (int j = 0; j < 4; ++j) b[j] = Bs[kk][tx*4+j];
            #pragma unroll
            for (int i = 0; i < 4; ++i)
                #pragma unroll
                for (int j = 0; j < 4; ++j) acc[i][j] += a[i]*b[j];
        }
        __syncthreads();
    }
    #pragma unroll
    for (int i = 0; i < 4; ++i) {
        int d = db + ty*4 + i;
        if (d >= Dn) continue;
        #pragma unroll
        for (int j = 0; j < 4; ++j) {
            int e = eb + tx*4 + j;
            if (e < Dn) fund[(size_t)bh*Dn*Dn + (size_t)d*Dn + e] = acc[i][j];
        }
    }
}

// ---------------------------------------------------------------------------
// K5: out[b,d2,o] = sum_{h,d1} fund[b,h,d1,d2] * W_pf[o, h*262+d1] + b_pf[o]
// ---------------------------------------------------------------------------
__global__ __launch_bounds__(256) void out_gemm(const float* __restrict__ fund,
                                                const float* __restrict__ Wpf,
                                                const float* __restrict__ bpf,
                                                float* __restrict__ out) {
    __shared__ float As[16][68];
    __shared__ float Bs[16][68];
    int tid = threadIdx.x;
    int b_ = blockIdx.z;
    int d2b = blockIdx.y * 64, ob = blockIdx.x * 64;
    int ty = tid >> 4, tx = tid & 15;
    int arow = tid >> 4, ac4 = (tid & 15) << 2;
    int brow = tid >> 2, bj4 = (tid & 3) << 2;
    float acc[4][4] = {};

    for (int jc = 0; jc < 786; jc += 16) {
        int j = jc + arow;
        int h  = j / Dn;
        int d1 = j - h*Dn;
        #pragma unroll
        for (int jj = 0; jj < 4; ++jj) {
            int d2 = d2b + ac4 + jj;
            float v = 0.0f;
            if (j < 786 && d2 < Dn)
                v = fund[((size_t)(b_*Hn + h)*Dn + d1)*Dn + d2];
            As[arow][ac4+jj] = v;
        }
        #pragma unroll
        for (int jj = 0; jj < 4; ++jj) {
            int j2 = jc + bj4 + jj;
            Bs[bj4+jj][brow] = (j2 < 786) ? Wpf[(size_t)(ob + brow)*786 + j2] : 0.0f;
        }
        __syncthreads();
        #pragma unroll
        for (int kk = 0; kk < 16; ++kk) {
            float a[4], b[4];
            #pragma unroll
            for (int i = 0; i < 4; ++i) a[i] = As[kk][ty*4+i];
            #pragma unroll
            for (int j2 = 0; j2 < 4; ++j2) b[j2] = Bs[kk][tx*4+j2];
            #pragma unroll
            for (int i = 0; i < 4; ++i)
                #pragma unroll
                for (int j2 = 0; j2 < 4; ++j2) acc[i][j2] += a[i]*b[j2];
        }
        __syncthreads();
    }
    #pragma unroll
    for (int i = 0; i < 4; ++i) {
        int d2 = d2b + ty*4 + i;
        if (d2 >= Dn) continue;
        #pragma unroll
        for (int j = 0; j < 4; ++j) {
            int o = ob + tx*4 + j;
            out[((size_t)b_*Dn + d2)*DIMn + o] = acc[i][j] + bpf[o];
        }
    }
}

// ---------------------------------------------------------------------------
extern "C" void kernel_launch(void* const* d_in, const int* in_sizes, int n_in,
                              void* d_out, int out_size, void* d_ws, size_t ws_size,
                              hipStream_t stream) {
    const float* x    = (const float*)d_in[0];   // [4,3072,768]
    const float* Wqkv = (const float*)d_in[1];   // [2304,768]
    const float* Wpf  = (const float*)d_in[2];   // [768,786]
    const float* bpf  = (const float*)d_in[3];   // [768]
    float* out = (float*)d_out;                  // [4,262,768]

    char* p = (char*)d_ws;
    u16* qh    = (u16*)p;                       p += (size_t)BHn*Nn*HDn*2;   // 18.87 MB
    u16* kh    = (u16*)p;                       p += (size_t)BHn*Nn*HDn*2;   // 18.87 MB
    u16* vT    = (u16*)p;                       p += (size_t)BHn*EP*Nn*2;    // 20.05 MB
    u16* vTs   = (u16*)p;                       p += (size_t)BHn*EP*Nn*2;    // 20.05 MB
    float* R   = (float*)p;                     p += (size_t)BHn*Nn*4;
    float* Cc  = (float*)p;                     p += (size_t)BHn*Nn*4;
    float* iR  = (float*)p;                     p += (size_t)BHn*Nn*4;
    float* iC  = (float*)p;                     p += (size_t)BHn*Nn*4;
    float* f1a = (float*)p;                     p += (size_t)BHn*Nn*Dn*4;    // 38.63 MB
    float* fund= (float*)p;                     p += (size_t)BHn*Dn*Dn*4;    // 3.29 MB

    hipMemsetAsync(R, 0, (size_t)2*BHn*Nn*sizeof(float), stream);

    qkv_mfma <<<dim3(36, 192), 256, 0, stream>>>(x, Wqkv, qh, kh, vT);
    pos_fill <<<dim3(BHn*16*Nn/256), 256, 0, stream>>>(vT);
    rc_mfma  <<<dim3(Nn/64, Nn/64, BHn), 256, 0, stream>>>(qh, kh, R, Cc);
    inv_kernel<<<dim3(BHn*Nn/256), 256, 0, stream>>>(R, Cc, iR, iC);
    scale_v  <<<dim3(BHn*EP*Nn/8/256), 256, 0, stream>>>(vT, iC, vTs);
    f1a_mfma <<<dim3(Nn/64, BHn), 256, 0, stream>>>(qh, kh, vTs, iR, f1a);
    fund_gemm<<<dim3(5, 5, BHn), 256, 0, stream>>>(vT, f1a, fund);
    out_gemm <<<dim3(DIMn/64, 5, Bn), 256, 0, stream>>>(fund, Wpf, bpf, out);
}

// Round 4
// 1262.759 us; speedup vs baseline: 6.1539x; 1.1552x over previous
//
#include <hip/hip_runtime.h>

typedef unsigned short u16;
typedef u16 u16x8 __attribute__((ext_vector_type(8)));
typedef u16 u16x4 __attribute__((ext_vector_type(4)));
typedef __bf16 bf16x8 __attribute__((ext_vector_type(8)));
typedef float f32x4 __attribute__((ext_vector_type(4)));

#define Bn   4
#define Nn   3072
#define DIMn 768
#define Hn   3
#define HDn  256
#define BHn  12
#define Dn   262
#define EP   272      // e-rows padded to 17*16

__device__ __forceinline__ u16 f2bf(float f) {
    unsigned u = __builtin_bit_cast(unsigned, f);
    u += 0x7fffu + ((u >> 16) & 1u);
    return (u16)(u >> 16);
}
__device__ __forceinline__ float bf2f(u16 h) {
    unsigned u = ((unsigned)h) << 16;
    return __builtin_bit_cast(float, u);
}
__device__ __forceinline__ bf16x8 ld_frag16(const u16* p) {   // 16B-aligned LDS read
    return *(const bf16x8*)p;
}
__device__ __forceinline__ bf16x8 ld_frag8(const u16* p) {    // 8B-aligned (2x b64)
    union { u16x4 h[2]; bf16x8 v; } u;
    u.h[0] = *(const u16x4*)p;
    u.h[1] = *(const u16x4*)(p + 4);
    return u.v;
}
#define MFMA(a,b,c) __builtin_amdgcn_mfma_f32_16x16x32_bf16(a, b, c, 0, 0, 0)

// ---------------------------------------------------------------------------
// K1: qkv = x @ W_qkv^T via MFMA. Writes qh/kh bf16 [bh][n][256] and
// vT bf16 [bh][272][3072] (v transposed; rows 256..271 filled by pos_fill).
// ---------------------------------------------------------------------------
__global__ __launch_bounds__(256) void qkv_mfma(const float* __restrict__ x,
                                                const float* __restrict__ W,
                                                u16* __restrict__ qh,
                                                u16* __restrict__ kh,
                                                u16* __restrict__ vT) {
    __shared__ u16 Xs[64*72];
    __shared__ u16 Ws[64*72];
    __shared__ u16 Cs[64*72];
    int tid = threadIdx.x;
    int w = tid >> 6, lane = tid & 63, quad = lane >> 4, l15 = lane & 15;
    int cb = blockIdx.x, rb = blockIdx.y;
    int r0 = rb * 64;
    int b_ = rb / 48;
    int n0 = (rb % 48) * 64;
    int which = cb / 12;             // 0:q 1:k 2:v
    int c0l = (cb % 12) * 64;        // col base within 768
    int h = c0l >> 8, hd0 = c0l & 255;
    int bh = b_ * Hn + h;
    int wr = w >> 1, wc = w & 1;

    f32x4 acc[2][2];
    #pragma unroll
    for (int i = 0; i < 2; ++i)
        #pragma unroll
        for (int j = 0; j < 2; ++j) acc[i][j] = (f32x4){0.f,0.f,0.f,0.f};

    for (int k0 = 0; k0 < DIMn; k0 += 64) {
        __syncthreads();
        #pragma unroll
        for (int i = 0; i < 4; ++i) {
            int e = tid + i*256;
            int row = e >> 4, c4 = (e & 15) * 4;
            float4 xv = *(const float4*)(x + (size_t)(r0 + row)*DIMn + k0 + c4);
            float4 wv = *(const float4*)(W + (size_t)(which*768 + c0l + row)*DIMn + k0 + c4);
            u16x4 xp, wp;
            xp[0]=f2bf(xv.x); xp[1]=f2bf(xv.y); xp[2]=f2bf(xv.z); xp[3]=f2bf(xv.w);
            wp[0]=f2bf(wv.x); wp[1]=f2bf(wv.y); wp[2]=f2bf(wv.z); wp[3]=f2bf(wv.w);
            *(u16x4*)&Xs[row*72 + c4] = xp;
            *(u16x4*)&Ws[row*72 + c4] = wp;
        }
        __syncthreads();
        #pragma unroll
        for (int ks = 0; ks < 2; ++ks) {
            bf16x8 a0 = ld_frag16(&Xs[(wr*32 +  0 + l15)*72 + ks*32 + quad*8]);
            bf16x8 a1 = ld_frag16(&Xs[(wr*32 + 16 + l15)*72 + ks*32 + quad*8]);
            bf16x8 b0 = ld_frag16(&Ws[(wc*32 +  0 + l15)*72 + ks*32 + quad*8]);
            bf16x8 b1 = ld_frag16(&Ws[(wc*32 + 16 + l15)*72 + ks*32 + quad*8]);
            acc[0][0] = MFMA(a0, b0, acc[0][0]);
            acc[0][1] = MFMA(a0, b1, acc[0][1]);
            acc[1][0] = MFMA(a1, b0, acc[1][0]);
            acc[1][1] = MFMA(a1, b1, acc[1][1]);
        }
    }
    __syncthreads();
    // write C tiles to Cs (transposed for v)
    #pragma unroll
    for (int rt = 0; rt < 2; ++rt)
        #pragma unroll
        for (int ct = 0; ct < 2; ++ct)
            #pragma unroll
            for (int r = 0; r < 4; ++r) {
                int row = wr*32 + rt*16 + quad*4 + r;
                int col = wc*32 + ct*16 + l15;
                u16 v = f2bf(acc[rt][ct][r]);
                if (which < 2) Cs[row*72 + col] = v;
                else           Cs[col*72 + row] = v;
            }
    __syncthreads();
    #pragma unroll
    for (int i = 0; i < 2; ++i) {
        int u = tid + i*256;
        int row = u >> 3, seg = u & 7;
        u16x8 vv = *(const u16x8*)&Cs[row*72 + seg*8];
        if (which == 0)
            *(u16x8*)(qh + ((size_t)bh*Nn + n0 + row)*HDn + hd0 + seg*8) = vv;
        else if (which == 1)
            *(u16x8*)(kh + ((size_t)bh*Nn + n0 + row)*HDn + hd0 + seg*8) = vv;
        else
            *(u16x8*)(vT + ((size_t)bh*EP + hd0 + row)*Nn + n0 + seg*8) = vv;
    }
}

// ---------------------------------------------------------------------------
// K1b: positional rows 256..261 of vT; zero rows 262..271.
// ---------------------------------------------------------------------------
__global__ void pos_fill(u16* __restrict__ vT) {
    int idx = blockIdx.x * blockDim.x + threadIdx.x;   // over BH*16*N
    int bh = idx / (16*Nn);
    int rem = idx - bh*16*Nn;
    int row = rem / Nn;        // 0..15
    int n = rem - row*Nn;
    int gy = n % 48, gx = n / 48;
    float p3 = -1.0f + (2.0f/47.0f)*gy;
    float p4 = -1.0f + (2.0f/63.0f)*gx;
    float v = 0.f;
    if (row == 0) v = p3*p3;
    else if (row == 1) v = p4*p4;
    else if (row == 2) v = p3*p4;
    else if (row == 3) v = p3;
    else if (row == 4) v = p4;
    else if (row == 5) v = 1.0f;
    vT[((size_t)bh*EP + 256 + row)*Nn + n] = f2bf(v);
}

// ---------------------------------------------------------------------------
// K2 v2: R[n]=sum_m exp(S), C[m]=sum_n exp(S); S^T=K·Q^T.
// Block = (m-half, n-tile 64, bh). Q-frags in regs, K-only LDS (33.8 KB ->
// 4 blocks/CU). R accumulated in-register over the block's m-half (atomic
// once at end); C partials atomically added per chunk.
// ---------------------------------------------------------------------------
__global__ __launch_bounds__(256) void rc_mfma(const u16* __restrict__ qh,
                                               const u16* __restrict__ kh,
                                               float* __restrict__ R,
                                               float* __restrict__ C) {
    __shared__ u16 Ks[64*264];            // doubles as Q staging during preload
    int tid = threadIdx.x;
    int w = tid >> 6, lane = tid & 63, quad = lane >> 4, l15 = lane & 15;
    int bh = blockIdx.z;
    int n0 = blockIdx.y * 64;
    int mhalf = blockIdx.x;               // 0 or 1
    const u16* qp = qh + ((size_t)bh*Nn + n0)*HDn;
    const u16* kp = kh + (size_t)bh*Nn*HDn;
    int wm = w & 1, wn = w >> 1;

    // stage Q tile into Ks region, preload fragments, then overwrite with K
    #pragma unroll
    for (int i = 0; i < 8; ++i) {
        int e = tid + i*256;
        int row = e >> 5, seg = e & 31;
        *(u16x8*)&Ks[row*264 + seg*8] = *(const u16x8*)(qp + (size_t)row*HDn + seg*8);
    }
    __syncthreads();
    bf16x8 qf[2][8];
    #pragma unroll
    for (int nt = 0; nt < 2; ++nt)
        #pragma unroll
        for (int ks = 0; ks < 8; ++ks)
            qf[nt][ks] = ld_frag16(&Ks[((2*wn+nt)*16 + l15)*264 + ks*32 + quad*8]);

    float rAcc[2] = {0.f, 0.f};
    for (int mc = 0; mc < Nn/128; ++mc) {
        int m0 = mhalf*(Nn/2) + mc*64;
        __syncthreads();       // qf reads (mc=0) / previous MFMA reads done
        #pragma unroll
        for (int i = 0; i < 8; ++i) {
            int e = tid + i*256;
            int row = e >> 5, seg = e & 31;
            *(u16x8*)&Ks[row*264 + seg*8] =
                *(const u16x8*)(kp + (size_t)(m0 + row)*HDn + seg*8);
        }
        __syncthreads();
        f32x4 sacc[2][2];
        #pragma unroll
        for (int i = 0; i < 2; ++i)
            #pragma unroll
            for (int j = 0; j < 2; ++j) sacc[i][j] = (f32x4){0.f,0.f,0.f,0.f};
        #pragma unroll
        for (int ks = 0; ks < 8; ++ks) {
            bf16x8 a0 = ld_frag16(&Ks[((2*wm+0)*16 + l15)*264 + ks*32 + quad*8]);
            bf16x8 a1 = ld_frag16(&Ks[((2*wm+1)*16 + l15)*264 + ks*32 + quad*8]);
            sacc[0][0] = MFMA(a0, qf[0][ks], sacc[0][0]);
            sacc[0][1] = MFMA(a0, qf[1][ks], sacc[0][1]);
            sacc[1][0] = MFMA(a1, qf[0][ks], sacc[1][0]);
            sacc[1][1] = MFMA(a1, qf[1][ks], sacc[1][1]);
        }
        float ex[2][2][4];
        #pragma unroll
        for (int mt = 0; mt < 2; ++mt)
            #pragma unroll
            for (int nt = 0; nt < 2; ++nt)
                #pragma unroll
                for (int r = 0; r < 4; ++r)
                    ex[mt][nt][r] = __expf(0.0625f * sacc[mt][nt][r]);
        #pragma unroll
        for (int nt = 0; nt < 2; ++nt)
            #pragma unroll
            for (int mt = 0; mt < 2; ++mt)
                #pragma unroll
                for (int r = 0; r < 4; ++r) rAcc[nt] += ex[mt][nt][r];
        // C partial: reduce over the wave's 32 n (shfl over l15), add
        #pragma unroll
        for (int mt = 0; mt < 2; ++mt)
            #pragma unroll
            for (int r = 0; r < 4; ++r) {
                float cp = ex[mt][0][r] + ex[mt][1][r];
                cp += __shfl_xor(cp, 1, 16);
                cp += __shfl_xor(cp, 2, 16);
                cp += __shfl_xor(cp, 4, 16);
                cp += __shfl_xor(cp, 8, 16);
                if (l15 == 0)
                    atomicAdd(&C[(size_t)bh*Nn + m0 + (2*wm+mt)*16 + quad*4 + r], cp);
            }
    }
    // R: reduce over quad (m-rows within wave), then atomic across wm/blocks
    #pragma unroll
    for (int nt = 0; nt < 2; ++nt) {
        float rp = rAcc[nt];
        rp += __shfl_xor(rp, 16, 64);
        rp += __shfl_xor(rp, 32, 64);
        if (quad == 0)
            atomicAdd(&R[(size_t)bh*Nn + n0 + (2*wn+nt)*16 + l15], rp);
    }
}

// ---------------------------------------------------------------------------
// K2b: invR = 1/R, invC = 1/C
// ---------------------------------------------------------------------------
__global__ void inv_kernel(const float* __restrict__ R, const float* __restrict__ C,
                           float* __restrict__ iR, float* __restrict__ iC) {
    int i = blockIdx.x * blockDim.x + threadIdx.x;
    iR[i] = 1.0f / R[i];
    iC[i] = 1.0f / C[i];
}

// ---------------------------------------------------------------------------
// K3: f1aT[e][n] = invR[n] * sum_m exp(0.125*raw(n,m))*invC[m] * vT[e][m]
// Software-pipelined: K/V chunks prefetched into regs during compute.
// invC folded into the Ps bf16 pack. Output bf16, transposed for fund MFMA.
// NOTE: et loops MUST have compile-time trip counts with wave-uniform guards;
// a runtime trip count demotes acc[][] to scratch (3 GB of HBM writes, R2 bug).
// ---------------------------------------------------------------------------
__global__ __launch_bounds__(256, 2) void f1a_mfma(const u16* __restrict__ qh,
                                                   const u16* __restrict__ kh,
                                                   const u16* __restrict__ vT,
                                                   const float* __restrict__ iR,
                                                   const float* __restrict__ iC,
                                                   u16* __restrict__ f1aT) {
    __shared__ u16 Ks[64*264];                  // 33792 B
    __shared__ u16 Bpool[EP*72 + 64*68];        // Vt(39168B) + Ps(8704B)
    u16* Vt = Bpool;
    u16* Ps = Bpool + EP*72;
    u16* Qs = Bpool;                            // overlay during preload
    int tid = threadIdx.x;
    int w = tid >> 6, lane = tid & 63, quad = lane >> 4, l15 = lane & 15;
    int bh = blockIdx.y, n0 = blockIdx.x * 64;
    const u16* qp = qh + ((size_t)bh*Nn + n0)*HDn;
    const u16* kp = kh + (size_t)bh*Nn*HDn;
    const u16* vp = vT + (size_t)bh*EP*Nn;
    int wm = w & 1, wn = w >> 1;

    // stage Q tile (Bpool overlay) and preload Q-fragments into registers
    #pragma unroll
    for (int i = 0; i < 8; ++i) {
        int e = tid + i*256;
        int row = e >> 5, seg = e & 31;
        *(u16x8*)&Qs[row*264 + seg*8] = *(const u16x8*)(qp + (size_t)row*HDn + seg*8);
    }
    __syncthreads();
    bf16x8 qf[2][8];
    #pragma unroll
    for (int nt = 0; nt < 2; ++nt)
        #pragma unroll
        for (int ks = 0; ks < 8; ++ks)
            qf[nt][ks] = ld_frag16(&Qs[((2*wn+nt)*16 + l15)*264 + ks*32 + quad*8]);

    // prefetch-address decomposition
    const int kr = tid >> 5, ksg = tid & 31;    // K: rows kr+8i, seg ksg
    const int vr = tid >> 3, vsg = tid & 7;     // V: rows vr+32i, seg vsg
    u16x8 kreg[8], vreg[9];
    // prefetch chunk 0
    #pragma unroll
    for (int i = 0; i < 8; ++i)
        kreg[i] = *(const u16x8*)(kp + (size_t)(kr + 8*i)*HDn + ksg*8);
    #pragma unroll
    for (int i = 0; i < 9; ++i)
        if (i < 8 || tid < 128)
            vreg[i] = *(const u16x8*)(vp + (size_t)(vr + 32*i)*Nn + vsg*8);

    const int et0 = w*4;                // wave w owns e-tiles et0..; wave 3 gets 5th
    f32x4 acc[4][5];
    #pragma unroll
    for (int a = 0; a < 4; ++a)
        #pragma unroll
        for (int b = 0; b < 5; ++b) acc[a][b] = (f32x4){0.f,0.f,0.f,0.f};

    for (int mc = 0; mc < Nn/64; ++mc) {
        int m0 = mc * 64;
        int m0n = (mc + 1 < Nn/64) ? (mc + 1)*64 : 0;   // clamped next chunk
        __syncthreads();   // qf/prev-PV readers of Bpool + Ks done
        // write prefetched chunk into LDS
        #pragma unroll
        for (int i = 0; i < 8; ++i)
            *(u16x8*)&Ks[(kr + 8*i)*264 + ksg*8] = kreg[i];
        #pragma unroll
        for (int i = 0; i < 9; ++i)
            if (i < 8 || tid < 128)
                *(u16x8*)&Vt[(vr + 32*i)*72 + vsg*8] = vreg[i];
        __syncthreads();
        // issue prefetch for next chunk (overlaps all compute below)
        #pragma unroll
        for (int i = 0; i < 8; ++i)
            kreg[i] = *(const u16x8*)(kp + (size_t)(m0n + kr + 8*i)*HDn + ksg*8);
        #pragma unroll
        for (int i = 0; i < 9; ++i)
            if (i < 8 || tid < 128)
                vreg[i] = *(const u16x8*)(vp + (size_t)(vr + 32*i)*Nn + m0n + vsg*8);
        // iC for this wave's m rows (L2-hot)
        float4 ic0 = *(const float4*)(iC + (size_t)bh*Nn + m0 + (2*wm+0)*16 + quad*4);
        float4 ic1 = *(const float4*)(iC + (size_t)bh*Nn + m0 + (2*wm+1)*16 + quad*4);
        // S^T = K·Q^T  (C rows = m, cols = n)
        f32x4 sacc[2][2];
        #pragma unroll
        for (int i = 0; i < 2; ++i)
            #pragma unroll
            for (int j = 0; j < 2; ++j) sacc[i][j] = (f32x4){0.f,0.f,0.f,0.f};
        #pragma unroll
        for (int ks = 0; ks < 8; ++ks) {
            bf16x8 a0 = ld_frag16(&Ks[((2*wm+0)*16 + l15)*264 + ks*32 + quad*8]);
            bf16x8 a1 = ld_frag16(&Ks[((2*wm+1)*16 + l15)*264 + ks*32 + quad*8]);
            sacc[0][0] = MFMA(a0, qf[0][ks], sacc[0][0]);
            sacc[0][1] = MFMA(a0, qf[1][ks], sacc[0][1]);
            sacc[1][0] = MFMA(a1, qf[0][ks], sacc[1][0]);
            sacc[1][1] = MFMA(a1, qf[1][ks], sacc[1][1]);
        }
        // P = exp(2*S)*invC[m]; pack 4 m-contig bf16, write Ps[n][m]
        #pragma unroll
        for (int mt = 0; mt < 2; ++mt)
            #pragma unroll
            for (int nt = 0; nt < 2; ++nt) {
                u16x4 pk;
                #pragma unroll
                for (int r = 0; r < 4; ++r) {
                    float icv = (mt == 0) ? ((const float*)&ic0)[r] : ((const float*)&ic1)[r];
                    pk[r] = f2bf(__expf(0.125f * sacc[mt][nt][r]) * icv);
                }
                int n = (2*wn+nt)*16 + l15;
                int m = (2*wm+mt)*16 + quad*4;
                *(u16x4*)&Ps[n*68 + m] = pk;
            }
        __syncthreads();
        // PV: acc += P · V   (A = Ps[n][m], B = Vt[e][m])
        #pragma unroll
        for (int ks = 0; ks < 2; ++ks) {
            bf16x8 pa[4];
            #pragma unroll
            for (int nt = 0; nt < 4; ++nt)
                pa[nt] = ld_frag8(&Ps[(nt*16 + l15)*68 + ks*32 + quad*8]);
            #pragma unroll
            for (int et = 0; et < 5; ++et) {
                if (et0 + et < 17) {   // wave-uniform; compile-time indices
                    bf16x8 vb = ld_frag16(&Vt[((et0+et)*16 + l15)*72 + ks*32 + quad*8]);
                    #pragma unroll
                    for (int nt = 0; nt < 4; ++nt)
                        acc[nt][et] = MFMA(pa[nt], vb, acc[nt][et]);
                }
            }
        }
    }
    // epilogue: scale by invR[n], pack bf16, store transposed f1aT[e][n]
    #pragma unroll
    for (int nt = 0; nt < 4; ++nt) {
        float4 ir4 = *(const float4*)(iR + (size_t)bh*Nn + n0 + nt*16 + quad*4);
        #pragma unroll
        for (int et = 0; et < 5; ++et) {
            if (et0 + et < 17) {
                int e = (et0+et)*16 + l15;
                u16x4 ov;
                #pragma unroll
                for (int r = 0; r < 4; ++r)
                    ov[r] = f2bf(acc[nt][et][r] * ((const float*)&ir4)[r]);
                *(u16x4*)(f1aT + ((size_t)bh*EP + e)*Nn + n0 + nt*16 + quad*4) = ov;
            }
        }
    }
}

// ---------------------------------------------------------------------------
// K4: fund[d,e] = sum_n vT[d][n] * f1aT[e][n]  via MFMA (K=3072)
// ---------------------------------------------------------------------------
__global__ __launch_bounds__(256) void fund_mfma(const u16* __restrict__ vT,
                                                 const u16* __restrict__ f1aT,
                                                 float* __restrict__ fund) {
    __shared__ u16 At[64*136];
    __shared__ u16 Bt[64*136];
    int tid = threadIdx.x;
    int w = tid >> 6, lane = tid & 63, quad = lane >> 4, l15 = lane & 15;
    int bh = blockIdx.z;
    int d0 = blockIdx.y * 64, e0 = blockIdx.x * 64;
    const u16* ap = vT   + (size_t)bh*EP*Nn;
    const u16* bp = f1aT + (size_t)bh*EP*Nn;
    int wd = w & 1, we = w >> 1;
    const u16x8 zero8 = {0,0,0,0,0,0,0,0};

    f32x4 acc[2][2];
    #pragma unroll
    for (int i = 0; i < 2; ++i)
        #pragma unroll
        for (int j = 0; j < 2; ++j) acc[i][j] = (f32x4){0.f,0.f,0.f,0.f};

    for (int nc = 0; nc < Nn; nc += 128) {
        __syncthreads();
        #pragma unroll
        for (int i = 0; i < 4; ++i) {
            int u = tid + i*256;
            int row = u >> 4, seg = u & 15;
            int da = d0 + row, eb = e0 + row;
            *(u16x8*)&At[row*136 + seg*8] = (da < EP)
                ? *(const u16x8*)(ap + (size_t)da*Nn + nc + seg*8) : zero8;
            *(u16x8*)&Bt[row*136 + seg*8] = (eb < EP)
                ? *(const u16x8*)(bp + (size_t)eb*Nn + nc + seg*8) : zero8;
        }
        __syncthreads();
        #pragma unroll
        for (int ks = 0; ks < 4; ++ks) {
            bf16x8 a0 = ld_frag16(&At[((2*wd+0)*16 + l15)*136 + ks*32 + quad*8]);
            bf16x8 a1 = ld_frag16(&At[((2*wd+1)*16 + l15)*136 + ks*32 + quad*8]);
            bf16x8 b0 = ld_frag16(&Bt[((2*we+0)*16 + l15)*136 + ks*32 + quad*8]);
            bf16x8 b1 = ld_frag16(&Bt[((2*we+1)*16 + l15)*136 + ks*32 + quad*8]);
            acc[0][0] = MFMA(a0, b0, acc[0][0]);
            acc[0][1] = MFMA(a0, b1, acc[0][1]);
            acc[1][0] = MFMA(a1, b0, acc[1][0]);
            acc[1][1] = MFMA(a1, b1, acc[1][1]);
        }
    }
    #pragma unroll
    for (int dt = 0; dt < 2; ++dt)
        #pragma unroll
        for (int et = 0; et < 2; ++et)
            #pragma unroll
            for (int r = 0; r < 4; ++r) {
                int d = d0 + (2*wd+dt)*16 + quad*4 + r;
                int e = e0 + (2*we+et)*16 + l15;
                if (d < Dn && e < Dn)
                    fund[(size_t)bh*Dn*Dn + (size_t)d*Dn + e] = acc[dt][et][r];
            }
}

// ---------------------------------------------------------------------------
// K5: out[b,d2,o] = sum_{h,d1} fund[b,h,d1,d2] * W_pf[o, h*262+d1] + b_pf[o]
// ---------------------------------------------------------------------------
__global__ __launch_bounds__(256) void out_gemm(const float* __restrict__ fund,
                                                const float* __restrict__ Wpf,
                                                const float* __restrict__ bpf,
                                                float* __restrict__ out) {
    __shared__ float As[16][68];
    __shared__ float Bs[16][68];
    int tid = threadIdx.x;
    int b_ = blockIdx.z;
    int d2b = blockIdx.y * 64, ob = blockIdx.x * 64;
    int ty = tid >> 4, tx = tid & 15;
    int arow = tid >> 4, ac4 = (tid & 15) << 2;
    int brow = tid >> 2, bj4 = (tid & 3) << 2;
    float acc[4][4] = {};

    for (int jc = 0; jc < 786; jc += 16) {
        int j = jc + arow;
        int h  = j / Dn;
        int d1 = j - h*Dn;
        #pragma unroll
        for (int jj = 0; jj < 4; ++jj) {
            int d2 = d2b + ac4 + jj;
            float v = 0.0f;
            if (j < 786 && d2 < Dn)
                v = fund[((size_t)(b_*Hn + h)*Dn + d1)*Dn + d2];
            As[arow][ac4+jj] = v;
        }
        #pragma unroll
        for (int jj = 0; jj < 4; ++jj) {
            int j2 = jc + bj4 + jj;
            Bs[bj4+jj][brow] = (j2 < 786) ? Wpf[(size_t)(ob + brow)*786 + j2] : 0.0f;
        }
        __syncthreads();
        #pragma unroll
        for (int kk = 0; kk < 16; ++kk) {
            float a[4], b[4];
            #pragma unroll
            for (int i = 0; i < 4; ++i) a[i] = As[kk][ty*4+i];
            #pragma unroll
            for (int j2 = 0; j2 < 4; ++j2) b[j2] = Bs[kk][tx*4+j2];
            #pragma unroll
            for (int i = 0; i < 4; ++i)
                #pragma unroll
                for (int j2 = 0; j2 < 4; ++j2) acc[i][j2] += a[i]*b[j2];
        }
        __syncthreads();
    }
    #pragma unroll
    for (int i = 0; i < 4; ++i) {
        int d2 = d2b + ty*4 + i;
        if (d2 >= Dn) continue;
        #pragma unroll
        for (int j = 0; j < 4; ++j) {
            int o = ob + tx*4 + j;
            out[((size_t)b_*Dn + d2)*DIMn + o] = acc[i][j] + bpf[o];
        }
    }
}

// ---------------------------------------------------------------------------
extern "C" void kernel_launch(void* const* d_in, const int* in_sizes, int n_in,
                              void* d_out, int out_size, void* d_ws, size_t ws_size,
                              hipStream_t stream) {
    const float* x    = (const float*)d_in[0];   // [4,3072,768]
    const float* Wqkv = (const float*)d_in[1];   // [2304,768]
    const float* Wpf  = (const float*)d_in[2];   // [768,786]
    const float* bpf  = (const float*)d_in[3];   // [768]
    float* out = (float*)d_out;                  // [4,262,768]

    char* p = (char*)d_ws;
    u16* qh    = (u16*)p;                       p += (size_t)BHn*Nn*HDn*2;   // 18.87 MB
    u16* kh    = (u16*)p;                       p += (size_t)BHn*Nn*HDn*2;   // 18.87 MB
    u16* vT    = (u16*)p;                       p += (size_t)BHn*EP*Nn*2;    // 20.05 MB
    u16* f1aT  = (u16*)p;                       p += (size_t)BHn*EP*Nn*2;    // 20.05 MB
    float* R   = (float*)p;                     p += (size_t)BHn*Nn*4;
    float* Cc  = (float*)p;                     p += (size_t)BHn*Nn*4;
    float* iR  = (float*)p;                     p += (size_t)BHn*Nn*4;
    float* iC  = (float*)p;                     p += (size_t)BHn*Nn*4;
    float* fund= (float*)p;                     p += (size_t)BHn*Dn*Dn*4;    // 3.29 MB

    hipMemsetAsync(R, 0, (size_t)2*BHn*Nn*sizeof(float), stream);

    qkv_mfma <<<dim3(36, 192), 256, 0, stream>>>(x, Wqkv, qh, kh, vT);
    pos_fill <<<dim3(BHn*16*Nn/256), 256, 0, stream>>>(vT);
    rc_mfma  <<<dim3(2, Nn/64, BHn), 256, 0, stream>>>(qh, kh, R, Cc);
    inv_kernel<<<dim3(BHn*Nn/256), 256, 0, stream>>>(R, Cc, iR, iC);
    f1a_mfma <<<dim3(Nn/64, BHn), 256, 0, stream>>>(qh, kh, vT, iR, iC, f1aT);
    fund_mfma<<<dim3(5, 5, BHn), 256, 0, stream>>>(vT, f1aT, fund);
    out_gemm <<<dim3(DIMn/64, 5, Bn), 256, 0, stream>>>(fund, Wpf, bpf, out);
}

// Round 6
// 798.691 us; speedup vs baseline: 9.7296x; 1.5810x over previous
//
#include <hip/hip_runtime.h>

typedef unsigned short u16;
typedef u16 u16x8 __attribute__((ext_vector_type(8)));
typedef u16 u16x4 __attribute__((ext_vector_type(4)));
typedef __bf16 bf16x8 __attribute__((ext_vector_type(8)));
typedef float f32x4 __attribute__((ext_vector_type(4)));

#define Bn   4
#define Nn   3072
#define DIMn 768
#define Hn   3
#define HDn  256
#define BHn  12
#define Dn   262
#define EP   272      // e-rows padded to 17*16

__device__ __forceinline__ u16 f2bf(float f) {
    unsigned u = __builtin_bit_cast(unsigned, f);
    u += 0x7fffu + ((u >> 16) & 1u);
    return (u16)(u >> 16);
}
__device__ __forceinline__ float bf2f(u16 h) {
    unsigned u = ((unsigned)h) << 16;
    return __builtin_bit_cast(float, u);
}
__device__ __forceinline__ bf16x8 ld_frag16(const u16* p) {   // 16B-aligned LDS read
    return *(const bf16x8*)p;
}
__device__ __forceinline__ bf16x8 ld_frag8(const u16* p) {    // 8B-aligned (2x b64)
    union { u16x4 h[2]; bf16x8 v; } u;
    u.h[0] = *(const u16x4*)p;
    u.h[1] = *(const u16x4*)(p + 4);
    return u.v;
}
#define MFMA(a,b,c) __builtin_amdgcn_mfma_f32_16x16x32_bf16(a, b, c, 0, 0, 0)

// ---------------------------------------------------------------------------
// K0: fp32 -> bf16 elementwise (x and W pre-conversion)
// ---------------------------------------------------------------------------
__global__ void to_bf16(const float* __restrict__ in, u16* __restrict__ out, int n8) {
    int i = blockIdx.x * blockDim.x + threadIdx.x;
    if (i >= n8) return;
    float4 a = *(const float4*)(in + (size_t)i*8);
    float4 b = *(const float4*)(in + (size_t)i*8 + 4);
    u16x8 o;
    o[0]=f2bf(a.x); o[1]=f2bf(a.y); o[2]=f2bf(a.z); o[3]=f2bf(a.w);
    o[4]=f2bf(b.x); o[5]=f2bf(b.y); o[6]=f2bf(b.z); o[7]=f2bf(b.w);
    *(u16x8*)(out + (size_t)i*8) = o;
}

// ---------------------------------------------------------------------------
// K1: qkv = x @ W_qkv^T via MFMA (bf16 inputs, register-prefetch pipeline).
// Writes qh/kh bf16 [bh][n][256] and vT bf16 [bh][272][3072] (transposed).
// ---------------------------------------------------------------------------
__global__ __launch_bounds__(256) void qkv_mfma(const u16* __restrict__ xb,
                                                const u16* __restrict__ Wb,
                                                u16* __restrict__ qh,
                                                u16* __restrict__ kh,
                                                u16* __restrict__ vT) {
    __shared__ u16 Xs[64*72];
    __shared__ u16 Ws[64*72];
    __shared__ u16 Cs[64*72];
    int tid = threadIdx.x;
    int w = tid >> 6, lane = tid & 63, quad = lane >> 4, l15 = lane & 15;
    int cb = blockIdx.x, rb = blockIdx.y;
    int r0 = rb * 64;
    int b_ = rb / 48;
    int n0 = (rb % 48) * 64;
    int which = cb / 12;             // 0:q 1:k 2:v
    int c0l = (cb % 12) * 64;        // col base within 768
    int h = c0l >> 8, hd0 = c0l & 255;
    int bh = b_ * Hn + h;
    int wr = w >> 1, wc = w & 1;
    const u16* xp = xb + (size_t)r0*DIMn;
    const u16* wp = Wb + (size_t)(which*768 + c0l)*DIMn;
    const int sr = tid >> 3, ssg = tid & 7;     // staging: rows sr+32i, seg ssg

    u16x8 xreg[2], wreg[2];
    #pragma unroll
    for (int i = 0; i < 2; ++i) {
        xreg[i] = *(const u16x8*)(xp + (size_t)(sr + 32*i)*DIMn + ssg*8);
        wreg[i] = *(const u16x8*)(wp + (size_t)(sr + 32*i)*DIMn + ssg*8);
    }

    f32x4 acc[2][2];
    #pragma unroll
    for (int i = 0; i < 2; ++i)
        #pragma unroll
        for (int j = 0; j < 2; ++j) acc[i][j] = (f32x4){0.f,0.f,0.f,0.f};

    for (int k0 = 0; k0 < DIMn; k0 += 64) {
        int k0n = (k0 + 64 < DIMn) ? k0 + 64 : 0;
        __syncthreads();
        #pragma unroll
        for (int i = 0; i < 2; ++i) {
            *(u16x8*)&Xs[(sr + 32*i)*72 + ssg*8] = xreg[i];
            *(u16x8*)&Ws[(sr + 32*i)*72 + ssg*8] = wreg[i];
        }
        __syncthreads();
        #pragma unroll
        for (int i = 0; i < 2; ++i) {
            xreg[i] = *(const u16x8*)(xp + (size_t)(sr + 32*i)*DIMn + k0n + ssg*8);
            wreg[i] = *(const u16x8*)(wp + (size_t)(sr + 32*i)*DIMn + k0n + ssg*8);
        }
        #pragma unroll
        for (int ks = 0; ks < 2; ++ks) {
            bf16x8 a0 = ld_frag16(&Xs[(wr*32 +  0 + l15)*72 + ks*32 + quad*8]);
            bf16x8 a1 = ld_frag16(&Xs[(wr*32 + 16 + l15)*72 + ks*32 + quad*8]);
            bf16x8 b0 = ld_frag16(&Ws[(wc*32 +  0 + l15)*72 + ks*32 + quad*8]);
            bf16x8 b1 = ld_frag16(&Ws[(wc*32 + 16 + l15)*72 + ks*32 + quad*8]);
            acc[0][0] = MFMA(a0, b0, acc[0][0]);
            acc[0][1] = MFMA(a0, b1, acc[0][1]);
            acc[1][0] = MFMA(a1, b0, acc[1][0]);
            acc[1][1] = MFMA(a1, b1, acc[1][1]);
        }
    }
    __syncthreads();
    // write C tiles to Cs (transposed for v)
    #pragma unroll
    for (int rt = 0; rt < 2; ++rt)
        #pragma unroll
        for (int ct = 0; ct < 2; ++ct)
            #pragma unroll
            for (int r = 0; r < 4; ++r) {
                int row = wr*32 + rt*16 + quad*4 + r;
                int col = wc*32 + ct*16 + l15;
                u16 v = f2bf(acc[rt][ct][r]);
                if (which < 2) Cs[row*72 + col] = v;
                else           Cs[col*72 + row] = v;
            }
    __syncthreads();
    #pragma unroll
    for (int i = 0; i < 2; ++i) {
        int u = tid + i*256;
        int row = u >> 3, seg = u & 7;
        u16x8 vv = *(const u16x8*)&Cs[row*72 + seg*8];
        if (which == 0)
            *(u16x8*)(qh + ((size_t)bh*Nn + n0 + row)*HDn + hd0 + seg*8) = vv;
        else if (which == 1)
            *(u16x8*)(kh + ((size_t)bh*Nn + n0 + row)*HDn + hd0 + seg*8) = vv;
        else
            *(u16x8*)(vT + ((size_t)bh*EP + hd0 + row)*Nn + n0 + seg*8) = vv;
    }
}

// ---------------------------------------------------------------------------
// K1b: positional rows 256..261 of vT; zero rows 262..271.
// ---------------------------------------------------------------------------
__global__ void pos_fill(u16* __restrict__ vT) {
    int idx = blockIdx.x * blockDim.x + threadIdx.x;   // over BH*16*N
    int bh = idx / (16*Nn);
    int rem = idx - bh*16*Nn;
    int row = rem / Nn;        // 0..15
    int n = rem - row*Nn;
    int gy = n % 48, gx = n / 48;
    float p3 = -1.0f + (2.0f/47.0f)*gy;
    float p4 = -1.0f + (2.0f/63.0f)*gx;
    float v = 0.f;
    if (row == 0) v = p3*p3;
    else if (row == 1) v = p4*p4;
    else if (row == 2) v = p3*p4;
    else if (row == 3) v = p3;
    else if (row == 4) v = p4;
    else if (row == 5) v = 1.0f;
    vT[((size_t)bh*EP + 256 + row)*Nn + n] = f2bf(v);
}

// ---------------------------------------------------------------------------
// K2 v3b: atomic-free R/C partials + register-prefetch pipeline.
// Block (mhalf, nb, bh). R_part[mhalf][bh][n] exclusive per block.
// C_part[nb*2+wn][bh][m] exclusive per (block, wn-wave-pair) — FIX for R5:
// the two wn wave-pairs hold different n-range partials of the SAME m and
// previously overwrote each other at one address; now each gets its own slot.
// ---------------------------------------------------------------------------
__global__ __launch_bounds__(256) void rc_mfma(const u16* __restrict__ qh,
                                               const u16* __restrict__ kh,
                                               float* __restrict__ R_part,
                                               float* __restrict__ C_part) {
    __shared__ u16 Ks[64*264];            // doubles as Q staging during preload
    __shared__ float rbuf[2][2][64];      // [wm][nt][wn*32 + l15]
    int tid = threadIdx.x;
    int w = tid >> 6, lane = tid & 63, quad = lane >> 4, l15 = lane & 15;
    int bh = blockIdx.z;
    int nb = blockIdx.y;
    int n0 = nb * 64;
    int mhalf = blockIdx.x;               // 0 or 1
    const u16* qp = qh + ((size_t)bh*Nn + n0)*HDn;
    const u16* kp = kh + (size_t)bh*Nn*HDn;
    int wm = w & 1, wn = w >> 1;

    // stage Q tile into Ks region, preload fragments, then overwrite with K
    #pragma unroll
    for (int i = 0; i < 8; ++i) {
        int e = tid + i*256;
        int row = e >> 5, seg = e & 31;
        *(u16x8*)&Ks[row*264 + seg*8] = *(const u16x8*)(qp + (size_t)row*HDn + seg*8);
    }
    __syncthreads();
    bf16x8 qf[2][8];
    #pragma unroll
    for (int nt = 0; nt < 2; ++nt)
        #pragma unroll
        for (int ks = 0; ks < 8; ++ks)
            qf[nt][ks] = ld_frag16(&Ks[((2*wn+nt)*16 + l15)*264 + ks*32 + quad*8]);

    const int kr = tid >> 5, ksg = tid & 31;
    u16x8 kreg[8];
    #pragma unroll
    for (int i = 0; i < 8; ++i)
        kreg[i] = *(const u16x8*)(kp + (size_t)(mhalf*(Nn/2) + kr + 8*i)*HDn + ksg*8);

    // exclusive C slot for this block's wn wave-pair
    float* cpart = C_part + ((size_t)(nb*2 + wn)*BHn + bh)*Nn;
    float rAcc[2] = {0.f, 0.f};
    for (int mc = 0; mc < Nn/128; ++mc) {
        int m0 = mhalf*(Nn/2) + mc*64;
        int m0n = mhalf*(Nn/2) + ((mc + 1 < Nn/128) ? (mc + 1)*64 : 0);
        __syncthreads();       // qf reads (mc=0) / previous MFMA reads done
        #pragma unroll
        for (int i = 0; i < 8; ++i)
            *(u16x8*)&Ks[(kr + 8*i)*264 + ksg*8] = kreg[i];
        __syncthreads();
        #pragma unroll
        for (int i = 0; i < 8; ++i)
            kreg[i] = *(const u16x8*)(kp + (size_t)(m0n + kr + 8*i)*HDn + ksg*8);
        f32x4 sacc[2][2];
        #pragma unroll
        for (int i = 0; i < 2; ++i)
            #pragma unroll
            for (int j = 0; j < 2; ++j) sacc[i][j] = (f32x4){0.f,0.f,0.f,0.f};
        #pragma unroll
        for (int ks = 0; ks < 8; ++ks) {
            bf16x8 a0 = ld_frag16(&Ks[((2*wm+0)*16 + l15)*264 + ks*32 + quad*8]);
            bf16x8 a1 = ld_frag16(&Ks[((2*wm+1)*16 + l15)*264 + ks*32 + quad*8]);
            sacc[0][0] = MFMA(a0, qf[0][ks], sacc[0][0]);
            sacc[0][1] = MFMA(a0, qf[1][ks], sacc[0][1]);
            sacc[1][0] = MFMA(a1, qf[0][ks], sacc[1][0]);
            sacc[1][1] = MFMA(a1, qf[1][ks], sacc[1][1]);
        }
        float ex[2][2][4];
        #pragma unroll
        for (int mt = 0; mt < 2; ++mt)
            #pragma unroll
            for (int nt = 0; nt < 2; ++nt)
                #pragma unroll
                for (int r = 0; r < 4; ++r)
                    ex[mt][nt][r] = __expf(0.0625f * sacc[mt][nt][r]);
        #pragma unroll
        for (int nt = 0; nt < 2; ++nt)
            #pragma unroll
            for (int mt = 0; mt < 2; ++mt)
                #pragma unroll
                for (int r = 0; r < 4; ++r) rAcc[nt] += ex[mt][nt][r];
        // C partial: reduce this wave's 32 n (nt regs + shfl over l15), store
        #pragma unroll
        for (int mt = 0; mt < 2; ++mt)
            #pragma unroll
            for (int r = 0; r < 4; ++r) {
                float cp = ex[mt][0][r] + ex[mt][1][r];
                cp += __shfl_xor(cp, 1, 16);
                cp += __shfl_xor(cp, 2, 16);
                cp += __shfl_xor(cp, 4, 16);
                cp += __shfl_xor(cp, 8, 16);
                if (l15 == 0)
                    cpart[m0 + (2*wm+mt)*16 + quad*4 + r] = cp;
            }
    }
    // R: shfl reduces quad (all 16 m-rows of each mt already in rAcc);
    // cross-wm combine via LDS; wm==0 quad==0 lanes write the exclusive slot.
    #pragma unroll
    for (int nt = 0; nt < 2; ++nt) {
        float rp = rAcc[nt];
        rp += __shfl_xor(rp, 16, 64);
        rp += __shfl_xor(rp, 32, 64);
        if (quad == 0) rbuf[wm][nt][wn*32 + l15] = rp;
    }
    __syncthreads();
    #pragma unroll
    for (int nt = 0; nt < 2; ++nt) {
        if (quad == 0 && wm == 0) {
            float tot = rbuf[0][nt][wn*32 + l15] + rbuf[1][nt][wn*32 + l15];
            R_part[(size_t)mhalf*BHn*Nn + (size_t)bh*Nn + n0 + (2*wn+nt)*16 + l15] = tot;
        }
    }
}

// ---------------------------------------------------------------------------
// K2b: iR = 1/sum(R_part over 2), iC = 1/sum(C_part over 96)
// ---------------------------------------------------------------------------
__global__ void inv_kernel(const float* __restrict__ R_part,
                           const float* __restrict__ C_part,
                           float* __restrict__ iR, float* __restrict__ iC) {
    int i = blockIdx.x * blockDim.x + threadIdx.x;   // over BHn*Nn
    float r = R_part[i] + R_part[(size_t)BHn*Nn + i];
    float c = 0.f;
    for (int s = 0; s < 96; ++s)
        c += C_part[(size_t)s*BHn*Nn + i];
    iR[i] = 1.0f / r;
    iC[i] = 1.0f / c;
}

// ---------------------------------------------------------------------------
// K3: f1aT[e][n] = invR[n] * sum_m exp(0.125*raw(n,m))*invC[m] * vT[e][m]
// Software-pipelined; invC folded into Ps pack; bf16 transposed output.
// NOTE: et loops MUST have compile-time trip counts with wave-uniform guards;
// a runtime trip count demotes acc[][] to scratch (3 GB of HBM writes, R2 bug).
// ---------------------------------------------------------------------------
__global__ __launch_bounds__(256, 2) void f1a_mfma(const u16* __restrict__ qh,
                                                   const u16* __restrict__ kh,
                                                   const u16* __restrict__ vT,
                                                   const float* __restrict__ iR,
                                                   const float* __restrict__ iC,
                                                   u16* __restrict__ f1aT) {
    __shared__ u16 Ks[64*264];                  // 33792 B
    __shared__ u16 Bpool[EP*72 + 64*68];        // Vt(39168B) + Ps(8704B)
    u16* Vt = Bpool;
    u16* Ps = Bpool + EP*72;
    u16* Qs = Bpool;                            // overlay during preload
    int tid = threadIdx.x;
    int w = tid >> 6, lane = tid & 63, quad = lane >> 4, l15 = lane & 15;
    int bh = blockIdx.y, n0 = blockIdx.x * 64;
    const u16* qp = qh + ((size_t)bh*Nn + n0)*HDn;
    const u16* kp = kh + (size_t)bh*Nn*HDn;
    const u16* vp = vT + (size_t)bh*EP*Nn;
    int wm = w & 1, wn = w >> 1;

    // stage Q tile (Bpool overlay) and preload Q-fragments into registers
    #pragma unroll
    for (int i = 0; i < 8; ++i) {
        int e = tid + i*256;
        int row = e >> 5, seg = e & 31;
        *(u16x8*)&Qs[row*264 + seg*8] = *(const u16x8*)(qp + (size_t)row*HDn + seg*8);
    }
    __syncthreads();
    bf16x8 qf[2][8];
    #pragma unroll
    for (int nt = 0; nt < 2; ++nt)
        #pragma unroll
        for (int ks = 0; ks < 8; ++ks)
            qf[nt][ks] = ld_frag16(&Qs[((2*wn+nt)*16 + l15)*264 + ks*32 + quad*8]);

    // prefetch-address decomposition
    const int kr = tid >> 5, ksg = tid & 31;    // K: rows kr+8i, seg ksg
    const int vr = tid >> 3, vsg = tid & 7;     // V: rows vr+32i, seg vsg
    u16x8 kreg[8], vreg[9];
    // prefetch chunk 0
    #pragma unroll
    for (int i = 0; i < 8; ++i)
        kreg[i] = *(const u16x8*)(kp + (size_t)(kr + 8*i)*HDn + ksg*8);
    #pragma unroll
    for (int i = 0; i < 9; ++i)
        if (i < 8 || tid < 128)
            vreg[i] = *(const u16x8*)(vp + (size_t)(vr + 32*i)*Nn + vsg*8);

    const int et0 = w*4;                // wave w owns e-tiles et0..; wave 3 gets 5th
    f32x4 acc[4][5];
    #pragma unroll
    for (int a = 0; a < 4; ++a)
        #pragma unroll
        for (int b = 0; b < 5; ++b) acc[a][b] = (f32x4){0.f,0.f,0.f,0.f};

    for (int mc = 0; mc < Nn/64; ++mc) {
        int m0 = mc * 64;
        int m0n = (mc + 1 < Nn/64) ? (mc + 1)*64 : 0;   // clamped next chunk
        __syncthreads();   // qf/prev-PV readers of Bpool + Ks done
        // write prefetched chunk into LDS
        #pragma unroll
        for (int i = 0; i < 8; ++i)
            *(u16x8*)&Ks[(kr + 8*i)*264 + ksg*8] = kreg[i];
        #pragma unroll
        for (int i = 0; i < 9; ++i)
            if (i < 8 || tid < 128)
                *(u16x8*)&Vt[(vr + 32*i)*72 + vsg*8] = vreg[i];
        __syncthreads();
        // issue prefetch for next chunk (overlaps all compute below)
        #pragma unroll
        for (int i = 0; i < 8; ++i)
            kreg[i] = *(const u16x8*)(kp + (size_t)(m0n + kr + 8*i)*HDn + ksg*8);
        #pragma unroll
        for (int i = 0; i < 9; ++i)
            if (i < 8 || tid < 128)
                vreg[i] = *(const u16x8*)(vp + (size_t)(vr + 32*i)*Nn + m0n + vsg*8);
        // iC for this wave's m rows (L2-hot)
        float4 ic0 = *(const float4*)(iC + (size_t)bh*Nn + m0 + (2*wm+0)*16 + quad*4);
        float4 ic1 = *(const float4*)(iC + (size_t)bh*Nn + m0 + (2*wm+1)*16 + quad*4);
        // S^T = K·Q^T  (C rows = m, cols = n)
        f32x4 sacc[2][2];
        #pragma unroll
        for (int i = 0; i < 2; ++i)
            #pragma unroll
            for (int j = 0; j < 2; ++j) sacc[i][j] = (f32x4){0.f,0.f,0.f,0.f};
        #pragma unroll
        for (int ks = 0; ks < 8; ++ks) {
            bf16x8 a0 = ld_frag16(&Ks[((2*wm+0)*16 + l15)*264 + ks*32 + quad*8]);
            bf16x8 a1 = ld_frag16(&Ks[((2*wm+1)*16 + l15)*264 + ks*32 + quad*8]);
            sacc[0][0] = MFMA(a0, qf[0][ks], sacc[0][0]);
            sacc[0][1] = MFMA(a0, qf[1][ks], sacc[0][1]);
            sacc[1][0] = MFMA(a1, qf[0][ks], sacc[1][0]);
            sacc[1][1] = MFMA(a1, qf[1][ks], sacc[1][1]);
        }
        // P = exp(2*S)*invC[m]; pack 4 m-contig bf16, write Ps[n][m]
        #pragma unroll
        for (int mt = 0; mt < 2; ++mt)
            #pragma unroll
            for (int nt = 0; nt < 2; ++nt) {
                u16x4 pk;
                #pragma unroll
                for (int r = 0; r < 4; ++r) {
                    float icv = (mt == 0) ? ((const float*)&ic0)[r] : ((const float*)&ic1)[r];
                    pk[r] = f2bf(__expf(0.125f * sacc[mt][nt][r]) * icv);
                }
                int n = (2*wn+nt)*16 + l15;
                int m = (2*wm+mt)*16 + quad*4;
                *(u16x4*)&Ps[n*68 + m] = pk;
            }
        __syncthreads();
        // PV: acc += P · V   (A = Ps[n][m], B = Vt[e][m])
        #pragma unroll
        for (int ks = 0; ks < 2; ++ks) {
            bf16x8 pa[4];
            #pragma unroll
            for (int nt = 0; nt < 4; ++nt)
                pa[nt] = ld_frag8(&Ps[(nt*16 + l15)*68 + ks*32 + quad*8]);
            #pragma unroll
            for (int et = 0; et < 5; ++et) {
                if (et0 + et < 17) {   // wave-uniform; compile-time indices
                    bf16x8 vb = ld_frag16(&Vt[((et0+et)*16 + l15)*72 + ks*32 + quad*8]);
                    #pragma unroll
                    for (int nt = 0; nt < 4; ++nt)
                        acc[nt][et] = MFMA(pa[nt], vb, acc[nt][et]);
                }
            }
        }
    }
    // epilogue: scale by invR[n], pack bf16, store transposed f1aT[e][n]
    #pragma unroll
    for (int nt = 0; nt < 4; ++nt) {
        float4 ir4 = *(const float4*)(iR + (size_t)bh*Nn + n0 + nt*16 + quad*4);
        #pragma unroll
        for (int et = 0; et < 5; ++et) {
            if (et0 + et < 17) {
                int e = (et0+et)*16 + l15;
                u16x4 ov;
                #pragma unroll
                for (int r = 0; r < 4; ++r)
                    ov[r] = f2bf(acc[nt][et][r] * ((const float*)&ir4)[r]);
                *(u16x4*)(f1aT + ((size_t)bh*EP + e)*Nn + n0 + nt*16 + quad*4) = ov;
            }
        }
    }
}

// ---------------------------------------------------------------------------
// K4: fund[d,e] = sum_n vT[d][n] * f1aT[e][n]  via MFMA (K=3072)
// ---------------------------------------------------------------------------
__global__ __launch_bounds__(256) void fund_mfma(const u16* __restrict__ vT,
                                                 const u16* __restrict__ f1aT,
                                                 float* __restrict__ fund) {
    __shared__ u16 At[64*136];
    __shared__ u16 Bt[64*136];
    int tid = threadIdx.x;
    int w = tid >> 6, lane = tid & 63, quad = lane >> 4, l15 = lane & 15;
    int bh = blockIdx.z;
    int d0 = blockIdx.y * 64, e0 = blockIdx.x * 64;
    const u16* ap = vT   + (size_t)bh*EP*Nn;
    const u16* bp = f1aT + (size_t)bh*EP*Nn;
    int wd = w & 1, we = w >> 1;
    const u16x8 zero8 = {0,0,0,0,0,0,0,0};

    f32x4 acc[2][2];
    #pragma unroll
    for (int i = 0; i < 2; ++i)
        #pragma unroll
        for (int j = 0; j < 2; ++j) acc[i][j] = (f32x4){0.f,0.f,0.f,0.f};

    for (int nc = 0; nc < Nn; nc += 128) {
        __syncthreads();
        #pragma unroll
        for (int i = 0; i < 4; ++i) {
            int u = tid + i*256;
            int row = u >> 4, seg = u & 15;
            int da = d0 + row, eb = e0 + row;
            *(u16x8*)&At[row*136 + seg*8] = (da < EP)
                ? *(const u16x8*)(ap + (size_t)da*Nn + nc + seg*8) : zero8;
            *(u16x8*)&Bt[row*136 + seg*8] = (eb < EP)
                ? *(const u16x8*)(bp + (size_t)eb*Nn + nc + seg*8) : zero8;
        }
        __syncthreads();
        #pragma unroll
        for (int ks = 0; ks < 4; ++ks) {
            bf16x8 a0 = ld_frag16(&At[((2*wd+0)*16 + l15)*136 + ks*32 + quad*8]);
            bf16x8 a1 = ld_frag16(&At[((2*wd+1)*16 + l15)*136 + ks*32 + quad*8]);
            bf16x8 b0 = ld_frag16(&Bt[((2*we+0)*16 + l15)*136 + ks*32 + quad*8]);
            bf16x8 b1 = ld_frag16(&Bt[((2*we+1)*16 + l15)*136 + ks*32 + quad*8]);
            acc[0][0] = MFMA(a0, b0, acc[0][0]);
            acc[0][1] = MFMA(a0, b1, acc[0][1]);
            acc[1][0] = MFMA(a1, b0, acc[1][0]);
            acc[1][1] = MFMA(a1, b1, acc[1][1]);
        }
    }
    #pragma unroll
    for (int dt = 0; dt < 2; ++dt)
        #pragma unroll
        for (int et = 0; et < 2; ++et)
            #pragma unroll
            for (int r = 0; r < 4; ++r) {
                int d = d0 + (2*wd+dt)*16 + quad*4 + r;
                int e = e0 + (2*we+et)*16 + l15;
                if (d < Dn && e < Dn)
                    fund[(size_t)bh*Dn*Dn + (size_t)d*Dn + e] = acc[dt][et][r];
            }
}

// ---------------------------------------------------------------------------
// K5: out[b,d2,o] = sum_{h,d1} fund[b,h,d1,d2] * W_pf[o, h*262+d1] + b_pf[o]
// ---------------------------------------------------------------------------
__global__ __launch_bounds__(256) void out_gemm(const float* __restrict__ fund,
                                                const float* __restrict__ Wpf,
                                                const float* __restrict__ bpf,
                                                float* __restrict__ out) {
    __shared__ float As[16][68];
    __shared__ float Bs[16][68];
    int tid = threadIdx.x;
    int b_ = blockIdx.z;
    int d2b = blockIdx.y * 64, ob = blockIdx.x * 64;
    int ty = tid >> 4, tx = tid & 15;
    int arow = tid >> 4, ac4 = (tid & 15) << 2;
    int brow = tid >> 2, bj4 = (tid & 3) << 2;
    float acc[4][4] = {};

    for (int jc = 0; jc < 786; jc += 16) {
        int j = jc + arow;
        int h  = j / Dn;
        int d1 = j - h*Dn;
        #pragma unroll
        for (int jj = 0; jj < 4; ++jj) {
            int d2 = d2b + ac4 + jj;
            float v = 0.0f;
            if (j < 786 && d2 < Dn)
                v = fund[((size_t)(b_*Hn + h)*Dn + d1)*Dn + d2];
            As[arow][ac4+jj] = v;
        }
        #pragma unroll
        for (int jj = 0; jj < 4; ++jj) {
            int j2 = jc + bj4 + jj;
            Bs[bj4+jj][brow] = (j2 < 786) ? Wpf[(size_t)(ob + brow)*786 + j2] : 0.0f;
        }
        __syncthreads();
        #pragma unroll
        for (int kk = 0; kk < 16; ++kk) {
            float a[4], b[4];
            #pragma unroll
            for (int i = 0; i < 4; ++i) a[i] = As[kk][ty*4+i];
            #pragma unroll
            for (int j2 = 0; j2 < 4; ++j2) b[j2] = Bs[kk][tx*4+j2];
            #pragma unroll
            for (int i = 0; i < 4; ++i)
                #pragma unroll
                for (int j2 = 0; j2 < 4; ++j2) acc[i][j2] += a[i]*b[j2];
        }
        __syncthreads();
    }
    #pragma unroll
    for (int i = 0; i < 4; ++i) {
        int d2 = d2b + ty*4 + i;
        if (d2 >= Dn) continue;
        #pragma unroll
        for (int j = 0; j < 4; ++j) {
            int o = ob + tx*4 + j;
            out[((size_t)b_*Dn + d2)*DIMn + o] = acc[i][j] + bpf[o];
        }
    }
}

// ---------------------------------------------------------------------------
extern "C" void kernel_launch(void* const* d_in, const int* in_sizes, int n_in,
                              void* d_out, int out_size, void* d_ws, size_t ws_size,
                              hipStream_t stream) {
    const float* x    = (const float*)d_in[0];   // [4,3072,768]
    const float* Wqkv = (const float*)d_in[1];   // [2304,768]
    const float* Wpf  = (const float*)d_in[2];   // [768,786]
    const float* bpf  = (const float*)d_in[3];   // [768]
    float* out = (float*)d_out;                  // [4,262,768]

    char* p = (char*)d_ws;
    u16* qh    = (u16*)p;                       p += (size_t)BHn*Nn*HDn*2;   // 18.87 MB
    u16* kh    = (u16*)p;                       p += (size_t)BHn*Nn*HDn*2;   // 18.87 MB
    u16* vT    = (u16*)p;                       p += (size_t)BHn*EP*Nn*2;    // 20.05 MB
    u16* f1aT  = (u16*)p;                       p += (size_t)BHn*EP*Nn*2;    // 20.05 MB
    u16* xb    = (u16*)p;                       p += (size_t)Bn*Nn*DIMn*2;   // 18.87 MB
    u16* Wb    = (u16*)p;                       p += (size_t)3*DIMn*DIMn*2;  // 3.54 MB
    float* Rp  = (float*)p;                     p += (size_t)2*BHn*Nn*4;     // 288 KB
    float* Cp  = (float*)p;                     p += (size_t)96*BHn*Nn*4;    // 14.16 MB
    float* iR  = (float*)p;                     p += (size_t)BHn*Nn*4;
    float* iC  = (float*)p;                     p += (size_t)BHn*Nn*4;
    float* fund= (float*)p;                     p += (size_t)BHn*Dn*Dn*4;    // 3.29 MB

    to_bf16  <<<dim3((Bn*Nn*DIMn/8 + 255)/256), 256, 0, stream>>>(x, xb, Bn*Nn*DIMn/8);
    to_bf16  <<<dim3((3*DIMn*DIMn/8 + 255)/256), 256, 0, stream>>>(Wqkv, Wb, 3*DIMn*DIMn/8);
    qkv_mfma <<<dim3(36, 192), 256, 0, stream>>>(xb, Wb, qh, kh, vT);
    pos_fill <<<dim3(BHn*16*Nn/256), 256, 0, stream>>>(vT);
    rc_mfma  <<<dim3(2, Nn/64, BHn), 256, 0, stream>>>(qh, kh, Rp, Cp);
    inv_kernel<<<dim3(BHn*Nn/256), 256, 0, stream>>>(Rp, Cp, iR, iC);
    f1a_mfma <<<dim3(Nn/64, BHn), 256, 0, stream>>>(qh, kh, vT, iR, iC, f1aT);
    fund_mfma<<<dim3(5, 5, BHn), 256, 0, stream>>>(vT, f1aT, fund);
    out_gemm <<<dim3(DIMn/64, 5, Bn), 256, 0, stream>>>(fund, Wpf, bpf, out);
}